// Round 26
// baseline (305.706 us; speedup 1.0000x reference)
//
#include <hip/hip_runtime.h>
#include <hip/hip_bf16.h>
#include <hip/hip_fp16.h>
#include <math.h>

#define Bq 2
#define Cq 64
#define Hq 192
#define Wq 192
#define HWq (Hq*Wq)            // 36864
#define Nq ((size_t)Bq*Cq*HWq) // 4718592

typedef __attribute__((ext_vector_type(8))) _Float16 f16x8;
typedef __attribute__((ext_vector_type(4))) float f32x4;

__device__ inline unsigned short h2us(__half h) {
  union { __half h; unsigned short u; } v; v.h = h; return v.u;
}

// ---------------------------------------------------------------------------
// MERGED prep: block 0 = small folds; blocks 1-9 = border; blocks 10-73 = big.
// ---------------------------------------------------------------------------
__global__ __launch_bounds__(256) void prep_all_kernel(
    const float* hc1_w, const float* hc1_b, const float* hc2_w, const float* hc2_b,
    const float* hc3_w, const float* hc3_b,
    const float* vc1_w, const float* vc1_b, const float* vc2_w, const float* vc2_b,
    const float* vc3_w, const float* vc3_b,
    const float* h_off_w, const float* h_off_b, const float* h_bn_g, const float* h_bn_b,
    const float* h_bn_m, const float* h_bn_v,
    const float* v_off_w, const float* v_off_b, const float* v_bn_g, const float* v_bn_b,
    const float* v_bn_m, const float* v_bn_v,
    const float* last_w, const float* last_g, const float* last_b, const float* last_m,
    const float* last_v,
    const float* __restrict__ w_first,
    const float* __restrict__ h_dsc_w, const float* __restrict__ v_dsc_w,
    float* wEffH, float* bEffH, float* wEffV, float* bEffV,
    float* wOffH, float* bOffH, float* wOffV, float* bOffV,
    float* lwT, float* lbO, float* wB,
    unsigned short* __restrict__ wtpH, unsigned short* __restrict__ wtpV,
    unsigned short* __restrict__ wpack)
{
  int bid = blockIdx.x;
  int t = threadIdx.x;
  if (bid == 0) {
    // ---- small folds ------------------------------------------------------
    if (t < 128) {
      int ch = t & 63;
      bool ish = t < 64;
      const float* w1p = (ish ? hc1_w : vc1_w) + ch*9;
      const float* w2p = (ish ? hc2_w : vc2_w) + ch*7;
      const float* w3p = (ish ? hc3_w : vc3_w) + ch*5;
      float w1r[9], w2r[7], w3r[5];
#pragma unroll
      for (int j = 0; j < 9; j++) w1r[j] = w1p[j];
#pragma unroll
      for (int k = 0; k < 7; k++) w2r[k] = w2p[k];
#pragma unroll
      for (int m = 0; m < 5; m++) w3r[m] = w3p[m];
      float t15[15];
#pragma unroll
      for (int s = 0; s < 15; s++) {
        float a = 0.f;
#pragma unroll
        for (int j = 0; j < 9; j++) { int k2 = s - j; if (k2 >= 0 && k2 < 7) a += w1r[j]*w2r[k2]; }
        t15[s] = a;
      }
      float* we = (ish ? wEffH : wEffV) + ch*19;
#pragma unroll
      for (int s = 0; s < 19; s++) {
        float a = 0.f;
#pragma unroll
        for (int j = 0; j < 15; j++) { int k3 = s - j; if (k3 >= 0 && k3 < 5) a += t15[j]*w3r[k3]; }
        we[s] = a;
      }
      float S2 = 0.f, S3 = 0.f;
#pragma unroll
      for (int j = 0; j < 7; j++) S2 += w2r[j];
#pragma unroll
      for (int j = 0; j < 5; j++) S3 += w3r[j];
      float b1 = (ish ? hc1_b : vc1_b)[ch];
      float b2 = (ish ? hc2_b : vc2_b)[ch];
      float b3 = (ish ? hc3_b : vc3_b)[ch];
      (ish ? bEffH : bEffV)[ch] = b1*S2*S3 + b2*S3 + b3;
    }
    for (int idx = t; idx < 9*64*7; idx += 256) {
      int tap = idx / 448; int rem = idx % 448; int i = rem / 7; int m = rem % 7;
      float invh = h_bn_g[m] / sqrtf(h_bn_v[m] + 1e-5f);
      wOffH[(tap*64 + i)*8 + m] = h_off_w[(m*64 + i)*9 + tap] * invh;
      float invv = v_bn_g[7+m] / sqrtf(v_bn_v[7+m] + 1e-5f);
      wOffV[(tap*64 + i)*8 + m] = v_off_w[((7+m)*64 + i)*9 + tap] * invv;
    }
    if (t < 7) {
      float invh = h_bn_g[t] / sqrtf(h_bn_v[t] + 1e-5f);
      bOffH[t] = h_off_b[t]*invh + h_bn_b[t] - h_bn_m[t]*invh;
      float invv = v_bn_g[7+t] / sqrtf(v_bn_v[7+t] + 1e-5f);
      bOffV[t] = v_off_b[7+t]*invv + v_bn_b[7+t] - v_bn_m[7+t]*invv;
    }
    for (int idx = t; idx < 4096; idx += 256) {
      int o = idx % 64; int i = idx / 64;
      float inv = last_g[o] / sqrtf(last_v[o] + 1e-3f);
      lwT[i*64 + o] = last_w[o*64 + i] * inv;
    }
    if (t < 64) {
      float inv = last_g[t] / sqrtf(last_v[t] + 1e-3f);
      lbO[t] = last_b[t] - last_m[t]*inv;
    }
  } else if (bid <= 9) {
    // ---- border composed weights ------------------------------------------
    int tid = (bid - 1)*256 + t;
    if (tid >= 2*64*18) return;
    int cls = tid % 18;
    int ch  = (tid / 18) % 64;
    int br  = tid / (18*64);
    int c = (cls < 9) ? cls : cls + 174;
    const float* w1p = (br==0 ? hc1_w : vc1_w) + ch*9;
    const float* w2p = (br==0 ? hc2_w : vc2_w) + ch*7;
    const float* w3p = (br==0 ? hc3_w : vc3_w) + ch*5;
    float b1 = (br==0 ? hc1_b : vc1_b)[ch];
    float b2 = (br==0 ? hc2_b : vc2_b)[ch];
    float b3 = (br==0 ? hc3_b : vc3_b)[ch];
    float w1r[9], w2r[7], w3r[5];
#pragma unroll
    for (int j = 0; j < 9; j++) w1r[j] = w1p[j];
#pragma unroll
    for (int k = 0; k < 7; k++) w2r[k] = w2p[k];
#pragma unroll
    for (int m = 0; m < 5; m++) w3r[m] = w3p[m];
    float acc[19];
#pragma unroll
    for (int s = 0; s < 19; s++) acc[s] = 0.f;
    float bacc = b3;
#pragma unroll
    for (int m = 0; m < 5; m++) {
      int d = c + m - 2;
      bool dok = (d >= 0 && d < Wq);
      float s2b = b2;
#pragma unroll
      for (int k = 0; k < 7; k++) {
        int e = d + k - 3;
        bool eok = (e >= 0 && e < Wq);
        if (eok) s2b += w2r[k] * b1;
        float wmk = w3r[m] * w2r[k];
#pragma unroll
        for (int j = 0; j < 9; j++) {
          int fd = e + j - 4;
          bool fok = (fd >= 0 && fd < Wq);
          float contrib = (dok && eok && fok) ? wmk * w1r[j] : 0.f;
          acc[m + k + j] += contrib;
        }
      }
      if (dok) bacc += w3r[m] * s2b;
    }
    float* dst = wB + ((size_t)(br*64 + ch)*18 + cls)*20;
#pragma unroll
    for (int s = 0; s < 19; s++) dst[s] = acc[s];
    dst[19] = bacc;
  } else {
    // ---- big packs --------------------------------------------------------
    int tid = (bid - 10)*256 + t;
    int nthr = 64*256;
    for (int idx = tid; idx < 7*2*2*64*32; idx += nthr) {
      int ch32 = idx & 31;
      int oc   = (idx >> 5) & 63;
      int hl   = (idx >> 11) & 1;
      int kc   = (idx >> 12) & 1;
      int tap  = idx >> 13;
      int i = kc*32 + ch32;
      float vh = h_dsc_w[oc*448 + i*7 + tap];
      float vv = v_dsc_w[oc*448 + i*7 + tap];
      _Float16 hh = (_Float16)vh;
      _Float16 hv = (_Float16)vv;
      unsigned short uh, uv;
      if (!hl) { uh = *(unsigned short*)&hh; uv = *(unsigned short*)&hv; }
      else {
        _Float16 lh = (_Float16)(vh - (float)hh);
        _Float16 lv = (_Float16)(vv - (float)hv);
        uh = *(unsigned short*)&lh; uv = *(unsigned short*)&lv;
      }
      wtpH[idx] = uh; wtpV[idx] = uv;
    }
    for (int e = tid; e < 2*49*2*64*32; e += nthr) {
      int ch  = e & 31;
      int oc  = (e >> 5) & 63;
      int hl  = (e >> 11) & 1;
      int rest = e >> 12;
      int tap = rest % 49;
      int h   = rest / 49;
      float wv = w_first[((size_t)oc*64 + h*32 + ch)*49 + tap];
      __half hh = __float2half(wv);
      unsigned short us;
      if (!hl) us = h2us(hh);
      else { float rr = wv - __half2float(hh); us = h2us(__float2half(rr)); }
      wpack[e] = us;
    }
  }
}

// ---------------------------------------------------------------------------
// x (NCHW f32) -> xpack single f16: [b][r][c][64]
// ---------------------------------------------------------------------------
__global__ __launch_bounds__(192) void tof16_pack_kernel(const float* __restrict__ x,
                                                         unsigned short* __restrict__ xpack)
{
  __shared__ unsigned int s[192*64];
  int r = blockIdx.x, b = blockIdx.y;
  int t = threadIdx.x;
  for (int ch = 0; ch < 64; ch++) {
    float v = x[((size_t)(b*64+ch)*Hq + r)*Wq + t];
    _Float16 hh = (_Float16)v;
    s[t*64 + (ch ^ (t & 31))] = (unsigned int)*(unsigned short*)&hh;
  }
  __syncthreads();
  unsigned short* dst = xpack + ((size_t)b*Hq + r)*Wq*64;
  for (int i = 0; i < 8; i++) {
    int gidx = i*192 + t;
    int c = gidx >> 3, g = gidx & 7;
    unsigned short tmp[8];
#pragma unroll
    for (int j = 0; j < 8; j++) {
      int ch = g*8 + j;
      tmp[j] = (unsigned short)s[c*64 + (ch ^ (c & 31))];
    }
    uint4 v;
    v.x = (unsigned int)tmp[0] | ((unsigned int)tmp[1] << 16);
    v.y = (unsigned int)tmp[2] | ((unsigned int)tmp[3] << 16);
    v.z = (unsigned int)tmp[4] | ((unsigned int)tmp[5] << 16);
    v.w = (unsigned int)tmp[6] | ((unsigned int)tmp[7] << 16);
    *(uint4*)(dst + (size_t)gidx*8) = v;
  }
}

// ---------------------------------------------------------------------------
// 7x7 conv via MFMA, 2-pass (x single f16, w hi/lo exact) — R23 validated.
// 2-row blocks: grid (4, 96, 2) = 768 blocks = 3/CU = 12 waves/CU.
// ---------------------------------------------------------------------------
__global__ __launch_bounds__(256) void conv7_mfma_kernel(
    const unsigned short* __restrict__ xpack,   // [b][r][c][64] f16
    const unsigned short* __restrict__ wpack,   // [h][tap][hl][oc][32] f16
    float* __restrict__ out)
{
  __shared__ __align__(16) unsigned short sA[8*54*32];   // 27648 B
  int ct = blockIdx.x;          // 0..3
  int rt = blockIdx.y;          // 0..95
  int b  = blockIdx.z;
  int r0 = rt*2, c0 = ct*48;
  int t = threadIdx.x;
  int wv = t >> 6;              // wave -> oc quarter
  int l  = t & 63;
  int l15 = l & 15, lg = l >> 4;
  int oc = wv*16 + l15;

  f32x4 acc[2][3];
#pragma unroll
  for (int i = 0; i < 2; i++)
#pragma unroll
    for (int j = 0; j < 3; j++) acc[i][j] = (f32x4){0.f,0.f,0.f,0.f};

  for (int h = 0; h < 2; h++) {
    __syncthreads();
    for (int idx = t; idx < 8*54*4; idx += 256) {
      int g = idx & 3, pix = idx >> 2;
      int row = pix / 54, col = pix % 54;
      int gr = r0 - 3 + row, gc = c0 - 3 + col;
      uint4 v = {0u,0u,0u,0u};
      if (gr >= 0 && gr < Hq && gc >= 0 && gc < Wq)
        v = *(const uint4*)(xpack + (((size_t)b*Hq + gr)*Wq + gc)*64 + (h*4 + g)*8);
      ((uint4*)sA)[(row*54 + col)*4 + (g ^ ((col >> 1) & 3))] = v;
    }
    __syncthreads();
    const unsigned short* wb = wpack + (size_t)h*49*4096;
#pragma unroll 7
    for (int tap = 0; tap < 49; tap++) {
      int dy = tap / 7, dx = tap % 7;
      f16x8 bh = *(const f16x8*)(wb + (size_t)tap*4096 +        oc*32 + lg*8);
      f16x8 bl = *(const f16x8*)(wb + (size_t)tap*4096 + 2048 + oc*32 + lg*8);
#pragma unroll
      for (int rw = 0; rw < 2; rw++) {
        int arow = rw + dy;
        f16x8 a[3];
#pragma unroll
        for (int tc = 0; tc < 3; tc++) {
          int col = tc*16 + l15 + dx;
          a[tc] = *(const f16x8*)((const uint4*)sA + (arow*54 + col)*4 + (lg ^ ((col >> 1) & 3)));
        }
#pragma unroll
        for (int tc = 0; tc < 3; tc++) {
          acc[rw][tc] = __builtin_amdgcn_mfma_f32_16x16x32_f16(a[tc], bh, acc[rw][tc], 0, 0, 0);
          acc[rw][tc] = __builtin_amdgcn_mfma_f32_16x16x32_f16(a[tc], bl, acc[rw][tc], 0, 0, 0);
        }
      }
    }
  }
#pragma unroll
  for (int rw = 0; rw < 2; rw++) {
    float* dst = out + ((size_t)(b*64 + oc)*Hq + (r0 + rw))*Wq + c0;
#pragma unroll
    for (int tc = 0; tc < 3; tc++) {
      f32x4 v = acc[rw][tc];
      *(float4*)(dst + tc*16 + lg*4) = make_float4(v[0], v[1], v[2], v[3]);
    }
  }
}

// ---------------------------------------------------------------------------
// FUSED separable 7x7 avg pool: one kernel, LDS-staged.
// ---------------------------------------------------------------------------
__global__ __launch_bounds__(256) void pool_fused_kernel(const float* __restrict__ in,
                                                         float* __restrict__ out)
{
  __shared__ float raw[38][192];
  __shared__ float cs[32][192];
  int rt = blockIdx.x;
  int plane = blockIdx.y;
  int r0 = rt*32;
  int t = threadIdx.x;
  const float* src = in + (size_t)plane*HWq;
  for (int idx = t; idx < 38*192; idx += 256) {
    int lr = idx / 192, c = idx % 192;
    int gr = r0 - 3 + lr;
    raw[lr][c] = (gr >= 0 && gr < Hq) ? src[gr*Wq + c] : 0.f;
  }
  __syncthreads();
  for (int idx = t; idx < 32*192; idx += 256) {
    int lr = idx / 192, c = idx % 192;
    float s = 0.f;
#pragma unroll
    for (int dr = 0; dr < 7; dr++) s += raw[lr + dr][c];
    cs[lr][c] = s;
  }
  __syncthreads();
  float* dst = out + (size_t)plane*HWq + r0*Wq;
  for (int idx = t; idx < 32*192; idx += 256) {
    int lr = idx / 192, c = idx % 192;
    float s = 0.f;
#pragma unroll
    for (int dc = -3; dc <= 3; dc++) {
      int cc = c + dc;
      if (cc >= 0 && cc < Wq) s += cs[lr][cc];
    }
    dst[idx] = s * (1.f/49.f);
  }
}

// ---------------------------------------------------------------------------
// MERGED fused depthwise 19-tap + f16 HI/LO plane-major pack [b][sub16][px][8].
// Grid (144, 8, 4): z = branch*2 + b.
// ---------------------------------------------------------------------------
__global__ __launch_bounds__(256) void dwf_kernel(const float* __restrict__ x1,
                                                  const float* __restrict__ wEffH,
                                                  const float* __restrict__ bEffH,
                                                  const float* __restrict__ wBH,
                                                  const float* __restrict__ wEffV,
                                                  const float* __restrict__ bEffV,
                                                  const float* __restrict__ wBV,
                                                  unsigned short* __restrict__ packH,
                                                  unsigned short* __restrict__ packV)
{
  __shared__ float sW[8][19][20];
  int z = blockIdx.z;
  int br = z >> 1, b = z & 1;
  const float* wEff = br ? wEffV : wEffH;
  const float* bEff = br ? bEffV : bEffH;
  const float* wB   = br ? wBV   : wBH;
  unsigned short* pack = br ? packV : packH;
  int g8 = blockIdx.y;
  int t = threadIdx.x;
  int chb = g8*8;
  for (int i = t; i < 8*380; i += 256) {
    int ch8 = i / 380; int rem = i % 380;
    int row = rem / 20, jj = rem % 20;
    int ch = chb + ch8;
    float v;
    if (row < 18) v = wB[((size_t)ch*18 + row)*20 + jj];
    else v = (jj < 19) ? wEff[ch*19 + jj] : bEff[ch];
    sW[ch8][row][jj] = v;
  }
  __syncthreads();
  int p = blockIdx.x*256 + t;
  int r = p / Wq, c = p % Wq;
  float vals[8];
  if (br == 0) {
    int row = (c < 9) ? c : ((c >= Wq-9) ? (c - 174) : 18);
#pragma unroll
    for (int ch8 = 0; ch8 < 8; ch8++) {
      const float* src = x1 + (size_t)(b*Cq + chb + ch8)*HWq + r*Wq;
      float s = sW[ch8][row][19];
#pragma unroll
      for (int j = 0; j < 19; j++) {
        int idx = min(max(c + j - 9, 0), Wq-1);
        s += src[idx] * sW[ch8][row][j];
      }
      vals[ch8] = s;
    }
  } else {
    int row = (r < 9) ? r : ((r >= Hq-9) ? (r - 174) : 18);
#pragma unroll
    for (int ch8 = 0; ch8 < 8; ch8++) {
      const float* src = x1 + (size_t)(b*Cq + chb + ch8)*HWq + c;
      float s = sW[ch8][row][19];
#pragma unroll
      for (int j = 0; j < 19; j++) {
        int idx = min(max(r + j - 9, 0), Hq-1);
        s += src[idx*Wq] * sW[ch8][row][j];
      }
      vals[ch8] = s;
    }
  }
  unsigned int hi[4], lo[4];
#pragma unroll
  for (int q = 0; q < 4; q++) {
    __half h0 = __float2half(vals[2*q]);
    __half h1 = __float2half(vals[2*q+1]);
    __half l0 = __float2half(vals[2*q]   - __half2float(h0));
    __half l1 = __float2half(vals[2*q+1] - __half2float(h1));
    hi[q] = (unsigned int)h2us(h0) | ((unsigned int)h2us(h1) << 16);
    lo[q] = (unsigned int)h2us(l0) | ((unsigned int)h2us(l1) << 16);
  }
  *(uint4*)(pack + (((size_t)b*16 + g8)*HWq + p)*8)     = make_uint4(hi[0], hi[1], hi[2], hi[3]);
  *(uint4*)(pack + (((size_t)b*16 + 8 + g8)*HWq + p)*8) = make_uint4(lo[0], lo[1], lo[2], lo[3]);
}

// ---------------------------------------------------------------------------
// MERGED offset conv + tanh + cum (reads HI+LO -> near-f32 offsets).
// 1D grid 576, XCD-PARTITIONED.
// ---------------------------------------------------------------------------
__global__ __launch_bounds__(256) void off_cum_kernel(const unsigned short* __restrict__ fpH,
                                                      const unsigned short* __restrict__ fpV,
                                                      const float* __restrict__ wOffH,
                                                      const float* __restrict__ bOffH,
                                                      const float* __restrict__ wOffV,
                                                      const float* __restrict__ bOffV,
                                                      float* __restrict__ hcum,
                                                      float* __restrict__ vcum)
{
  const size_t HW8 = (size_t)HWq*8;
  int bid = blockIdx.x;                 // 0..575
  int xcd = bid & 7, lid = bid >> 3;    // lid 0..71
  int combo = xcd >> 1;                 // 0..3
  int br = combo >> 1, b = combo & 1;
  int pxblk = (xcd & 1)*72 + lid;       // 0..143
  const unsigned short* fp = br ? fpV : fpH;
  const float* wOff = br ? wOffV : wOffH;
  const float* bOff = br ? bOffV : bOffH;
  float* cum = br ? vcum : hcum;
  int p = pxblk*256 + threadIdx.x;
  int r = p / Wq, c = p % Wq;
  float tv[7];
#pragma unroll
  for (int m = 0; m < 7; m++) tv[m] = bOff[m];
  const unsigned short* fb = fp + (size_t)b*HWq*128;
  for (int tap = 0; tap < 9; tap++) {
    int dy = tap/3 - 1, dx = tap%3 - 1;
    int rr = r + dy, cc = c + dx;
    if (rr < 0 || rr >= Hq || cc < 0 || cc >= Wq) continue;
    const unsigned short* p0 = fb + ((size_t)rr*Wq + cc)*8;
    const float* wp = wOff + tap*512;
    for (int g = 0; g < 8; g++) {
      f16x8 hv = *(const f16x8*)(p0 + (size_t)g*HW8);
      f16x8 lv = *(const f16x8*)(p0 + (size_t)(8 + g)*HW8);
#pragma unroll
      for (int e = 0; e < 8; e++) {
        float fv = (float)hv[e] + (float)lv[e];
        const float* wr = wp + (g*8 + e)*8;
#pragma unroll
        for (int m = 0; m < 7; m++) tv[m] += fv * wr[m];
      }
    }
  }
#pragma unroll
  for (int m = 0; m < 7; m++) tv[m] = tanhf(tv[m]);
  float c0 = tv[0], c1 = tv[1] + tv[2], c2 = tv[2], c3 = 0.f;
  float c4 = tv[4], c5 = tv[4] + tv[5], c6 = tv[6];
  size_t bb = (size_t)b*7*HWq + p;
  cum[bb + 0*HWq] = c0; cum[bb + 1*HWq] = c1; cum[bb + 2*HWq] = c2;
  cum[bb + 3*HWq] = c3; cum[bb + 4*HWq] = c4; cum[bb + 5*HWq] = c5;
  cum[bb + 6*HWq] = c6;
}

// ---------------------------------------------------------------------------
// MERGED deformable sample + einsum via MFMA v4: unified morph addressing,
// 2-DEEP software pipeline with A/B register buffer sets (16 loads in
// flight). Parity-unrolled 2-tap loop body keeps buffer indices static
// (no scratch). Numerics byte-identical to v3/R24.
// 32 px/wave, ch-split staging; BARRIER-FREE (intra-wave LDS, in-order DS).
// ---------------------------------------------------------------------------
__global__ __launch_bounds__(64, 3) void einsum_mfma_kernel(
    const unsigned short* __restrict__ fpH, const unsigned short* __restrict__ fpV,
    const float* __restrict__ cumH, const float* __restrict__ cumV,
    const unsigned short* __restrict__ wtpHp, const unsigned short* __restrict__ wtpVp,
    const float* __restrict__ dscbH, const float* __restrict__ dscbV,
    float* __restrict__ outH, float* __restrict__ outV,
    float* __restrict__ pstat)
{
  __shared__ __align__(16) unsigned short sA[2*32*64];  // 8 KB, 2 tap slots
  const size_t HW8 = (size_t)HWq*8;
  int morph = blockIdx.y;
  const unsigned short* fp  = morph ? fpV   : fpH;
  const float* cum          = morph ? cumV  : cumH;
  const unsigned short* wtp = morph ? wtpVp : wtpHp;
  const float* dsc_b        = morph ? dscbV : dscbH;
  float* out                = morph ? outV  : outH;
  int bid = blockIdx.x;                    // 0..2303
  int swz = (bid & 7)*288 + (bid >> 3);    // XCD-banded
  int b   = swz / 1152;
  int blk = swz % 1152;
  int l = threadIdx.x;                     // 0..63
  int l15 = l & 15, lg = l >> 4;
  int l7 = l & 7;
  int px5 = l & 31;                        // px within wave
  int chh = l >> 5;                        // channel half
  int p = blk*32 + px5;
  int r = p / Wq, c = p % Wq;

  int fixc   = morph ? r : c;              // coordinate that gets +k-3
  int vbase  = morph ? c : r;              // coordinate that gets cum offset
  int stride = morph ? 1 : Wq;

  f32x4 acc[2][4];
#pragma unroll
  for (int i = 0; i < 2; i++)
#pragma unroll
    for (int j = 0; j < 4; j++) acc[i][j] = (f32x4){0.f,0.f,0.f,0.f};

  const unsigned short* fb = fp + (size_t)b*HWq*128;

  f16x8 a0A[4], a1A[4], a0B[4], a1B[4];
  float w0A, w1A, w0B, w1B;
  bool oobA, oobB;

#define ISSUE(KK, A0R, A1R, W0, W1, OOB)                                    \
  {                                                                         \
    int fx = fixc + (KK) - 3;                                               \
    OOB = (fx < 0 || fx >= 192);                                            \
    float vf = (float)vbase + cum[((size_t)(b*7 + (KK)))*HWq + p];          \
    float v0 = floorf(vf);                                                  \
    int v0q = (int)v0;                                                      \
    int v0i = min(max(v0q, 0), 191);                                        \
    int v1i = min(max(v0q + 1, 0), 191);                                    \
    float v0f = fminf(fmaxf(v0, 0.f), 192.f);                               \
    float v1f = fminf(fmaxf(v0 + 1.f, 0.f), 192.f);                         \
    W0 = v1f - vf; W1 = vf - v0f;                                           \
    int fixoff = morph ? fx*Wq : fx;                                        \
    const unsigned short* p0 = fb + (size_t)(fixoff + v0i*stride)*8;        \
    const unsigned short* p1 = fb + (size_t)(fixoff + v1i*stride)*8;        \
    if (!(OOB)) {                                                           \
      _Pragma("unroll")                                                     \
      for (int gi = 0; gi < 4; gi++) {                                      \
        int g = chh*4 + gi;                                                 \
        A0R[gi] = *(const f16x8*)(p0 + (size_t)g*HW8);                      \
        A1R[gi] = *(const f16x8*)(p1 + (size_t)g*HW8);                      \
      }                                                                     \
    }                                                                       \
  }

#define WRITE(SLOT, A0R, A1R, W0, W1, OOB)                                  \
  {                                                                         \
    unsigned short* myrow = sA + (size_t)((SLOT)*32 + px5)*64;              \
    if (OOB) {                                                              \
      uint4 z = {0u,0u,0u,0u};                                              \
      _Pragma("unroll")                                                     \
      for (int gi = 0; gi < 4; gi++)                                        \
        *(uint4*)(myrow + (size_t)(((chh*4 + gi) ^ l7))*8) = z;             \
    } else {                                                                \
      _Pragma("unroll")                                                     \
      for (int gi = 0; gi < 4; gi++) {                                      \
        f16x8 sh;                                                           \
        _Pragma("unroll")                                                   \
        for (int e = 0; e < 8; e++) {                                       \
          float v = (W0)*(float)A0R[gi][e] + (W1)*(float)A1R[gi][e];        \
          sh[e] = (_Float16)v;                                              \
        }                                                                   \
        *(f16x8*)(myrow + (size_t)(((chh*4 + gi) ^ l7))*8) = sh;            \
      }                                                                     \
    }                                                                       \
  }

#define MFMA_TAP(KK, SLOT)                                                  \
  {                                                                         \
    _Pragma("unroll")                                                       \
    for (int kc = 0; kc < 2; kc++) {                                        \
      const unsigned short* wbase = wtp + (size_t)(((KK)*2 + kc)*2)*2048;   \
      f16x8 bh[4], bl[4];                                                   \
      _Pragma("unroll")                                                     \
      for (int tb = 0; tb < 4; tb++) {                                      \
        bh[tb] = *(const f16x8*)(wbase + (tb*16 + l15)*32 + lg*8);          \
        bl[tb] = *(const f16x8*)(wbase + 2048 + (tb*16 + l15)*32 + lg*8);   \
      }                                                                     \
      f16x8 ah[2];                                                          \
      _Pragma("unroll")                                                     \
      for (int ta = 0; ta < 2; ta++) {                                      \
        const unsigned short* rbase = sA + (size_t)((SLOT)*32 + ta*16 + l15)*64; \
        ah[ta] = *(const f16x8*)(rbase + (size_t)((kc*4 + lg) ^ l7)*8);     \
      }                                                                     \
      _Pragma("unroll")                                                     \
      for (int ta = 0; ta < 2; ta++)                                        \
        _Pragma("unroll")                                                   \
        for (int tb = 0; tb < 4; tb++) {                                    \
          acc[ta][tb] = __builtin_amdgcn_mfma_f32_16x16x32_f16(ah[ta], bh[tb], acc[ta][tb], 0, 0, 0); \
          acc[ta][tb] = __builtin_amdgcn_mfma_f32_16x16x32_f16(ah[ta], bl[tb], acc[ta][tb], 0, 0, 0); \
        }                                                                   \
    }                                                                       \
  }

  // prologue: 2 taps in flight
  ISSUE(0, a0A, a1A, w0A, w1A, oobA);
  ISSUE(1, a0B, a1B, w0B, w1B, oobB);
  WRITE(0, a0A, a1A, w0A, w1A, oobA);
  // steady state: taps (k,k+1) per iteration; buffer parity static.
  //   k even -> slot 0 / buffer A, k odd -> slot 1 / buffer B
#pragma unroll 1
  for (int k2 = 0; k2 < 3; k2++) {
    int k = k2*2;
    ISSUE(k+2, a0A, a1A, w0A, w1A, oobA);       // tap k+2 into A (A consumed)
    MFMA_TAP(k, 0);                             // compute tap k (slot 0)
    WRITE(1, a0B, a1B, w0B, w1B, oobB);         // tap k+1 -> slot 1
    if (k2 < 2) ISSUE(k+3, a0B, a1B, w0B, w1B, oobB);  // tap k+3 into B
    MFMA_TAP(k+1, 1);                           // compute tap k+1 (slot 1)
    WRITE(0, a0A, a1A, w0A, w1A, oobA);         // tap k+2 -> slot 0
  }
  MFMA_TAP(6, 0);                               // final tap
#undef ISSUE
#undef WRITE
#undef MFMA_TAP

  int pbase = blk*32;
#pragma unroll
  for (int tb = 0; tb < 4; tb++) {
    int oc = tb*16 + l15;
    float bias = dsc_b[oc];
    float* dst = out + (size_t)(b*64 + oc)*HWq + pbase;
    float s = 0.f, ss = 0.f;
#pragma unroll
    for (int ta = 0; ta < 2; ta++) {
      f32x4 v = acc[ta][tb];
      float v0 = v[0]+bias, v1 = v[1]+bias, v2 = v[2]+bias, v3 = v[3]+bias;
      *(float4*)(dst + ta*16 + lg*4) = make_float4(v0, v1, v2, v3);
      s  += v0 + v1 + v2 + v3;
      ss += v0*v0 + v1*v1 + v2*v2 + v3*v3;
    }
    s  += __shfl_xor(s, 16);
    s  += __shfl_xor(s, 32);
    ss += __shfl_xor(ss, 16);
    ss += __shfl_xor(ss, 32);
    if (lg == 0) {
      float* pp = pstat + ((size_t)(morph*2304 + swz))*128 + oc*2;
      pp[0] = s; pp[1] = ss;
    }
  }
}

// ---------------------------------------------------------------------------
// GN partial reduce: grid 256 (one block per (buf,b,ch)), reads pstat.
// ---------------------------------------------------------------------------
__global__ __launch_bounds__(256) void gnred_kernel(const float* __restrict__ pstat,
                                                    float* __restrict__ stats)
{
  int combo = blockIdx.x;           // buf*128 + b*64 + ch
  int buf = combo >> 7;
  int rem = combo & 127;
  int b = rem >> 6, ch = rem & 63;
  int t = threadIdx.x;
  float s = 0.f, ss = 0.f;
  for (int q = t; q < 1152; q += 256) {
    const float* pp = pstat + ((size_t)(buf*2304 + b*1152 + q))*128 + ch*2;
    s += pp[0]; ss += pp[1];
  }
  __shared__ float red[2][4];
  for (int off = 32; off; off >>= 1) {
    s  += __shfl_down(s, off);
    ss += __shfl_down(ss, off);
  }
  if ((t & 63) == 0) { red[0][t >> 6] = s; red[1][t >> 6] = ss; }
  __syncthreads();
  if (t == 0) {
    s  = red[0][0] + red[0][1] + red[0][2] + red[0][3];
    ss = red[1][0] + red[1][1] + red[1][2] + red[1][3];
    stats[combo*2 + 0] = s;
    stats[combo*2 + 1] = ss;
  }
}

__global__ __launch_bounds__(256) void gnfinal_kernel(const float* __restrict__ stats,
                                                      const float* __restrict__ h_gn_g, const float* __restrict__ h_gn_b,
                                                      const float* __restrict__ v_gn_g, const float* __restrict__ v_gn_b,
                                                      float* __restrict__ gnAB)
{
  int t = threadIdx.x;
  int buf = t >> 7, ch = t & 63;
  int base = t & ~3;
  float sum = 0.f, ss = 0.f;
#pragma unroll
  for (int q = 0; q < 4; q++) { sum += stats[(base+q)*2]; ss += stats[(base+q)*2 + 1]; }
  const float n = 4.f * HWq;
  float mean = sum / n;
  float var = ss / n - mean*mean;
  float gg = (buf ? v_gn_g : h_gn_g)[ch];
  float bb = (buf ? v_gn_b : h_gn_b)[ch];
  float A = gg / sqrtf(var + 1e-5f);
  gnAB[t*2 + 0] = A;
  gnAB[t*2 + 1] = bb - mean*A;
}

// ---------------------------------------------------------------------------
// FUSED: comb = relu(GN(h)) + relu(GN(v)) + x1 inline, then 1x1 conv + SiLU
// ---------------------------------------------------------------------------
__global__ __launch_bounds__(256) void final2_kernel(const float* __restrict__ hbuf,
                                                     const float* __restrict__ vbuf,
                                                     const float* __restrict__ x1,
                                                     const float* __restrict__ gnAB,
                                                     const float* __restrict__ lwT,
                                                     const float* __restrict__ lbO,
                                                     float* __restrict__ out)
{
  int b = blockIdx.y;
  int p = blockIdx.x*256 + threadIdx.x;
  float acc[64];
#pragma unroll
  for (int o = 0; o < 64; o++) acc[o] = 0.f;
  for (int i = 0; i < 64; i++) {
    size_t off = (size_t)(b*64 + i)*HWq + p;
    int plane = b*64 + i;
    int ih = plane*2;
    int iv = (128 + plane)*2;
    float hv = fmaxf(hbuf[off]*gnAB[ih] + gnAB[ih+1], 0.f);
    float vv = fmaxf(vbuf[off]*gnAB[iv] + gnAB[iv+1], 0.f);
    float cv = hv + vv + x1[off];
    const float* wr = lwT + i*64;
#pragma unroll
    for (int o = 0; o < 64; o++) acc[o] += cv * wr[o];
  }
  float* dst = out + (size_t)b*Cq*HWq + p;
#pragma unroll
  for (int o = 0; o < 64; o++) {
    float yv = acc[o] + lbO[o];
    dst[(size_t)o*HWq] = yv / (1.f + expf(-yv));
  }
}

// ---------------------------------------------------------------------------
extern "C" void kernel_launch(void* const* d_in, const int* in_sizes, int n_in,
                              void* d_out, int out_size, void* d_ws, size_t ws_size,
                              hipStream_t stream)
{
  const float* x       = (const float*)d_in[0];
  const float* w_first = (const float*)d_in[1];
  float* ws = (float*)d_ws;

  float* bufA = ws;            // conv7 out -> h-einsum-out
  float* bufB = ws + Nq;       // v-einsum-out
  float* x1   = ws + 2*Nq;
  float* h_ds = ws + 3*Nq;     // xpack -> fpackH
  float* v_ds = ws + 4*Nq;     // fpackV
  size_t off = 5*Nq;
  float* hcum  = ws + off; off += (size_t)Bq*7*HWq;
  float* vcum  = ws + off; off += (size_t)Bq*7*HWq;
  float* wEffH = ws + off; off += 64*19;
  float* bEffH = ws + off; off += 64;
  float* wEffV = ws + off; off += 64*19;
  float* bEffV = ws + off; off += 64;
  float* wtH   = ws + off; off += 64*64*7;   // holds wtpH f16 pack
  float* wtV   = ws + off; off += 64*64*7;   // holds wtpV f16 pack
  float* wOffH = ws + off; off += 9*64*8;
  float* bOffH = ws + off; off += 8;
  float* wOffV = ws + off; off += 9*64*8;
  float* bOffV = ws + off; off += 8;
  float* lwT   = ws + off; off += 64*64;
  float* lbO   = ws + off; off += 64;
  float* stats = ws + off; off += 512;
  float* gnAB  = ws + off; off += 512;
  float* wB    = ws + off; off += 2*64*18*20;
  float* pstat = ws + off; off += (size_t)2*2304*128;
  unsigned short* wpack = (unsigned short*)(ws + off); off += 2*49*2*64*32/2 + 16;
  unsigned short* xpack  = (unsigned short*)h_ds;
  unsigned short* fpackH = (unsigned short*)h_ds;
  unsigned short* fpackV = (unsigned short*)v_ds;
  unsigned short* wtpH = (unsigned short*)wtH;
  unsigned short* wtpV = (unsigned short*)wtV;

  prep_all_kernel<<<dim3(74), dim3(256), 0, stream>>>(
      (const float*)d_in[2],  (const float*)d_in[3],  (const float*)d_in[4],  (const float*)d_in[5],
      (const float*)d_in[6],  (const float*)d_in[7],
      (const float*)d_in[8],  (const float*)d_in[9],  (const float*)d_in[10], (const float*)d_in[11],
      (const float*)d_in[12], (const float*)d_in[13],
      (const float*)d_in[14], (const float*)d_in[15], (const float*)d_in[16], (const float*)d_in[17],
      (const float*)d_in[18], (const float*)d_in[19],
      (const float*)d_in[24], (const float*)d_in[25], (const float*)d_in[26], (const float*)d_in[27],
      (const float*)d_in[28], (const float*)d_in[29],
      (const float*)d_in[34], (const float*)d_in[35], (const float*)d_in[36], (const float*)d_in[37],
      (const float*)d_in[38],
      w_first, (const float*)d_in[20], (const float*)d_in[30],
      wEffH, bEffH, wEffV, bEffV, wOffH, bOffH, wOffV, bOffV, lwT, lbO, wB,
      wtpH, wtpV, wpack);

  tof16_pack_kernel<<<dim3(Hq, Bq), dim3(192), 0, stream>>>(x, xpack);
  conv7_mfma_kernel<<<dim3(4, 96, 2), dim3(256), 0, stream>>>(xpack, wpack, bufA);

  pool_fused_kernel<<<dim3(6, 128), dim3(256), 0, stream>>>(bufA, x1);

  dwf_kernel<<<dim3(144, 8, 4), dim3(256), 0, stream>>>(x1, wEffH, bEffH, wB,
      wEffV, bEffV, wB + 64*18*20, fpackH, fpackV);

  off_cum_kernel<<<dim3(576), dim3(256), 0, stream>>>(fpackH, fpackV,
      wOffH, bOffH, wOffV, bOffV, hcum, vcum);

  einsum_mfma_kernel<<<dim3(2304, 2), dim3(64), 0, stream>>>(fpackH, fpackV,
      hcum, vcum, wtpH, wtpV, (const float*)d_in[21], (const float*)d_in[31], bufA, bufB, pstat);

  gnred_kernel<<<dim3(256), dim3(256), 0, stream>>>(pstat, stats);
  gnfinal_kernel<<<dim3(1), dim3(256), 0, stream>>>(stats,
      (const float*)d_in[22], (const float*)d_in[23],
      (const float*)d_in[32], (const float*)d_in[33], gnAB);

  final2_kernel<<<dim3(144, 2), dim3(256), 0, stream>>>(bufA, bufB, x1, gnAB, lwT, lbO, (float*)d_out);
}

// Round 27
// 304.476 us; speedup vs baseline: 1.0040x; 1.0040x over previous
//
#include <hip/hip_runtime.h>
#include <hip/hip_bf16.h>
#include <hip/hip_fp16.h>
#include <math.h>

#define Bq 2
#define Cq 64
#define Hq 192
#define Wq 192
#define HWq (Hq*Wq)            // 36864
#define Nq ((size_t)Bq*Cq*HWq) // 4718592

typedef __attribute__((ext_vector_type(8))) _Float16 f16x8;
typedef __attribute__((ext_vector_type(4))) float f32x4;

__device__ inline unsigned short h2us(__half h) {
  union { __half h; unsigned short u; } v; v.h = h; return v.u;
}

// ---------------------------------------------------------------------------
// MERGED prep: block 0 = small folds; blocks 1-9 = border; blocks 10-73 = big.
// ---------------------------------------------------------------------------
__global__ __launch_bounds__(256) void prep_all_kernel(
    const float* hc1_w, const float* hc1_b, const float* hc2_w, const float* hc2_b,
    const float* hc3_w, const float* hc3_b,
    const float* vc1_w, const float* vc1_b, const float* vc2_w, const float* vc2_b,
    const float* vc3_w, const float* vc3_b,
    const float* h_off_w, const float* h_off_b, const float* h_bn_g, const float* h_bn_b,
    const float* h_bn_m, const float* h_bn_v,
    const float* v_off_w, const float* v_off_b, const float* v_bn_g, const float* v_bn_b,
    const float* v_bn_m, const float* v_bn_v,
    const float* last_w, const float* last_g, const float* last_b, const float* last_m,
    const float* last_v,
    const float* __restrict__ w_first,
    const float* __restrict__ h_dsc_w, const float* __restrict__ v_dsc_w,
    float* wEffH, float* bEffH, float* wEffV, float* bEffV,
    float* wOffH, float* bOffH, float* wOffV, float* bOffV,
    float* lwT, float* lbO, float* wB,
    unsigned short* __restrict__ wtpH, unsigned short* __restrict__ wtpV,
    unsigned short* __restrict__ wpack)
{
  int bid = blockIdx.x;
  int t = threadIdx.x;
  if (bid == 0) {
    // ---- small folds ------------------------------------------------------
    if (t < 128) {
      int ch = t & 63;
      bool ish = t < 64;
      const float* w1p = (ish ? hc1_w : vc1_w) + ch*9;
      const float* w2p = (ish ? hc2_w : vc2_w) + ch*7;
      const float* w3p = (ish ? hc3_w : vc3_w) + ch*5;
      float w1r[9], w2r[7], w3r[5];
#pragma unroll
      for (int j = 0; j < 9; j++) w1r[j] = w1p[j];
#pragma unroll
      for (int k = 0; k < 7; k++) w2r[k] = w2p[k];
#pragma unroll
      for (int m = 0; m < 5; m++) w3r[m] = w3p[m];
      float t15[15];
#pragma unroll
      for (int s = 0; s < 15; s++) {
        float a = 0.f;
#pragma unroll
        for (int j = 0; j < 9; j++) { int k2 = s - j; if (k2 >= 0 && k2 < 7) a += w1r[j]*w2r[k2]; }
        t15[s] = a;
      }
      float* we = (ish ? wEffH : wEffV) + ch*19;
#pragma unroll
      for (int s = 0; s < 19; s++) {
        float a = 0.f;
#pragma unroll
        for (int j = 0; j < 15; j++) { int k3 = s - j; if (k3 >= 0 && k3 < 5) a += t15[j]*w3r[k3]; }
        we[s] = a;
      }
      float S2 = 0.f, S3 = 0.f;
#pragma unroll
      for (int j = 0; j < 7; j++) S2 += w2r[j];
#pragma unroll
      for (int j = 0; j < 5; j++) S3 += w3r[j];
      float b1 = (ish ? hc1_b : vc1_b)[ch];
      float b2 = (ish ? hc2_b : vc2_b)[ch];
      float b3 = (ish ? hc3_b : vc3_b)[ch];
      (ish ? bEffH : bEffV)[ch] = b1*S2*S3 + b2*S3 + b3;
    }
    for (int idx = t; idx < 9*64*7; idx += 256) {
      int tap = idx / 448; int rem = idx % 448; int i = rem / 7; int m = rem % 7;
      float invh = h_bn_g[m] / sqrtf(h_bn_v[m] + 1e-5f);
      wOffH[(tap*64 + i)*8 + m] = h_off_w[(m*64 + i)*9 + tap] * invh;
      float invv = v_bn_g[7+m] / sqrtf(v_bn_v[7+m] + 1e-5f);
      wOffV[(tap*64 + i)*8 + m] = v_off_w[((7+m)*64 + i)*9 + tap] * invv;
    }
    if (t < 7) {
      float invh = h_bn_g[t] / sqrtf(h_bn_v[t] + 1e-5f);
      bOffH[t] = h_off_b[t]*invh + h_bn_b[t] - h_bn_m[t]*invh;
      float invv = v_bn_g[7+t] / sqrtf(v_bn_v[7+t] + 1e-5f);
      bOffV[t] = v_off_b[7+t]*invv + v_bn_b[7+t] - v_bn_m[7+t]*invv;
    }
    for (int idx = t; idx < 4096; idx += 256) {
      int o = idx % 64; int i = idx / 64;
      float inv = last_g[o] / sqrtf(last_v[o] + 1e-3f);
      lwT[i*64 + o] = last_w[o*64 + i] * inv;
    }
    if (t < 64) {
      float inv = last_g[t] / sqrtf(last_v[t] + 1e-3f);
      lbO[t] = last_b[t] - last_m[t]*inv;
    }
  } else if (bid <= 9) {
    // ---- border composed weights ------------------------------------------
    int tid = (bid - 1)*256 + t;
    if (tid >= 2*64*18) return;
    int cls = tid % 18;
    int ch  = (tid / 18) % 64;
    int br  = tid / (18*64);
    int c = (cls < 9) ? cls : cls + 174;
    const float* w1p = (br==0 ? hc1_w : vc1_w) + ch*9;
    const float* w2p = (br==0 ? hc2_w : vc2_w) + ch*7;
    const float* w3p = (br==0 ? hc3_w : vc3_w) + ch*5;
    float b1 = (br==0 ? hc1_b : vc1_b)[ch];
    float b2 = (br==0 ? hc2_b : vc2_b)[ch];
    float b3 = (br==0 ? hc3_b : vc3_b)[ch];
    float w1r[9], w2r[7], w3r[5];
#pragma unroll
    for (int j = 0; j < 9; j++) w1r[j] = w1p[j];
#pragma unroll
    for (int k = 0; k < 7; k++) w2r[k] = w2p[k];
#pragma unroll
    for (int m = 0; m < 5; m++) w3r[m] = w3p[m];
    float acc[19];
#pragma unroll
    for (int s = 0; s < 19; s++) acc[s] = 0.f;
    float bacc = b3;
#pragma unroll
    for (int m = 0; m < 5; m++) {
      int d = c + m - 2;
      bool dok = (d >= 0 && d < Wq);
      float s2b = b2;
#pragma unroll
      for (int k = 0; k < 7; k++) {
        int e = d + k - 3;
        bool eok = (e >= 0 && e < Wq);
        if (eok) s2b += w2r[k] * b1;
        float wmk = w3r[m] * w2r[k];
#pragma unroll
        for (int j = 0; j < 9; j++) {
          int fd = e + j - 4;
          bool fok = (fd >= 0 && fd < Wq);
          float contrib = (dok && eok && fok) ? wmk * w1r[j] : 0.f;
          acc[m + k + j] += contrib;
        }
      }
      if (dok) bacc += w3r[m] * s2b;
    }
    float* dst = wB + ((size_t)(br*64 + ch)*18 + cls)*20;
#pragma unroll
    for (int s = 0; s < 19; s++) dst[s] = acc[s];
    dst[19] = bacc;
  } else {
    // ---- big packs --------------------------------------------------------
    int tid = (bid - 10)*256 + t;
    int nthr = 64*256;
    for (int idx = tid; idx < 7*2*2*64*32; idx += nthr) {
      int ch32 = idx & 31;
      int oc   = (idx >> 5) & 63;
      int hl   = (idx >> 11) & 1;
      int kc   = (idx >> 12) & 1;
      int tap  = idx >> 13;
      int i = kc*32 + ch32;
      float vh = h_dsc_w[oc*448 + i*7 + tap];
      float vv = v_dsc_w[oc*448 + i*7 + tap];
      _Float16 hh = (_Float16)vh;
      _Float16 hv = (_Float16)vv;
      unsigned short uh, uv;
      if (!hl) { uh = *(unsigned short*)&hh; uv = *(unsigned short*)&hv; }
      else {
        _Float16 lh = (_Float16)(vh - (float)hh);
        _Float16 lv = (_Float16)(vv - (float)hv);
        uh = *(unsigned short*)&lh; uv = *(unsigned short*)&lv;
      }
      wtpH[idx] = uh; wtpV[idx] = uv;
    }
    for (int e = tid; e < 2*49*2*64*32; e += nthr) {
      int ch  = e & 31;
      int oc  = (e >> 5) & 63;
      int hl  = (e >> 11) & 1;
      int rest = e >> 12;
      int tap = rest % 49;
      int h   = rest / 49;
      float wv = w_first[((size_t)oc*64 + h*32 + ch)*49 + tap];
      __half hh = __float2half(wv);
      unsigned short us;
      if (!hl) us = h2us(hh);
      else { float rr = wv - __half2float(hh); us = h2us(__float2half(rr)); }
      wpack[e] = us;
    }
  }
}

// ---------------------------------------------------------------------------
// x (NCHW f32) -> xpack single f16: [b][r][c][64]
// ---------------------------------------------------------------------------
__global__ __launch_bounds__(192) void tof16_pack_kernel(const float* __restrict__ x,
                                                         unsigned short* __restrict__ xpack)
{
  __shared__ unsigned int s[192*64];
  int r = blockIdx.x, b = blockIdx.y;
  int t = threadIdx.x;
  for (int ch = 0; ch < 64; ch++) {
    float v = x[((size_t)(b*64+ch)*Hq + r)*Wq + t];
    _Float16 hh = (_Float16)v;
    s[t*64 + (ch ^ (t & 31))] = (unsigned int)*(unsigned short*)&hh;
  }
  __syncthreads();
  unsigned short* dst = xpack + ((size_t)b*Hq + r)*Wq*64;
  for (int i = 0; i < 8; i++) {
    int gidx = i*192 + t;
    int c = gidx >> 3, g = gidx & 7;
    unsigned short tmp[8];
#pragma unroll
    for (int j = 0; j < 8; j++) {
      int ch = g*8 + j;
      tmp[j] = (unsigned short)s[c*64 + (ch ^ (c & 31))];
    }
    uint4 v;
    v.x = (unsigned int)tmp[0] | ((unsigned int)tmp[1] << 16);
    v.y = (unsigned int)tmp[2] | ((unsigned int)tmp[3] << 16);
    v.z = (unsigned int)tmp[4] | ((unsigned int)tmp[5] << 16);
    v.w = (unsigned int)tmp[6] | ((unsigned int)tmp[7] << 16);
    *(uint4*)(dst + (size_t)gidx*8) = v;
  }
}

// ---------------------------------------------------------------------------
// 7x7 conv via MFMA, 2-pass (x single f16, w hi/lo exact) — R23 validated.
// 2-row blocks: grid (4, 96, 2) = 768 blocks = 3/CU = 12 waves/CU.
// ---------------------------------------------------------------------------
__global__ __launch_bounds__(256) void conv7_mfma_kernel(
    const unsigned short* __restrict__ xpack,   // [b][r][c][64] f16
    const unsigned short* __restrict__ wpack,   // [h][tap][hl][oc][32] f16
    float* __restrict__ out)
{
  __shared__ __align__(16) unsigned short sA[8*54*32];   // 27648 B
  int ct = blockIdx.x;          // 0..3
  int rt = blockIdx.y;          // 0..95
  int b  = blockIdx.z;
  int r0 = rt*2, c0 = ct*48;
  int t = threadIdx.x;
  int wv = t >> 6;              // wave -> oc quarter
  int l  = t & 63;
  int l15 = l & 15, lg = l >> 4;
  int oc = wv*16 + l15;

  f32x4 acc[2][3];
#pragma unroll
  for (int i = 0; i < 2; i++)
#pragma unroll
    for (int j = 0; j < 3; j++) acc[i][j] = (f32x4){0.f,0.f,0.f,0.f};

  for (int h = 0; h < 2; h++) {
    __syncthreads();
    for (int idx = t; idx < 8*54*4; idx += 256) {
      int g = idx & 3, pix = idx >> 2;
      int row = pix / 54, col = pix % 54;
      int gr = r0 - 3 + row, gc = c0 - 3 + col;
      uint4 v = {0u,0u,0u,0u};
      if (gr >= 0 && gr < Hq && gc >= 0 && gc < Wq)
        v = *(const uint4*)(xpack + (((size_t)b*Hq + gr)*Wq + gc)*64 + (h*4 + g)*8);
      ((uint4*)sA)[(row*54 + col)*4 + (g ^ ((col >> 1) & 3))] = v;
    }
    __syncthreads();
    const unsigned short* wb = wpack + (size_t)h*49*4096;
#pragma unroll 7
    for (int tap = 0; tap < 49; tap++) {
      int dy = tap / 7, dx = tap % 7;
      f16x8 bh = *(const f16x8*)(wb + (size_t)tap*4096 +        oc*32 + lg*8);
      f16x8 bl = *(const f16x8*)(wb + (size_t)tap*4096 + 2048 + oc*32 + lg*8);
#pragma unroll
      for (int rw = 0; rw < 2; rw++) {
        int arow = rw + dy;
        f16x8 a[3];
#pragma unroll
        for (int tc = 0; tc < 3; tc++) {
          int col = tc*16 + l15 + dx;
          a[tc] = *(const f16x8*)((const uint4*)sA + (arow*54 + col)*4 + (lg ^ ((col >> 1) & 3)));
        }
#pragma unroll
        for (int tc = 0; tc < 3; tc++) {
          acc[rw][tc] = __builtin_amdgcn_mfma_f32_16x16x32_f16(a[tc], bh, acc[rw][tc], 0, 0, 0);
          acc[rw][tc] = __builtin_amdgcn_mfma_f32_16x16x32_f16(a[tc], bl, acc[rw][tc], 0, 0, 0);
        }
      }
    }
  }
#pragma unroll
  for (int rw = 0; rw < 2; rw++) {
    float* dst = out + ((size_t)(b*64 + oc)*Hq + (r0 + rw))*Wq + c0;
#pragma unroll
    for (int tc = 0; tc < 3; tc++) {
      f32x4 v = acc[rw][tc];
      *(float4*)(dst + tc*16 + lg*4) = make_float4(v[0], v[1], v[2], v[3]);
    }
  }
}

// ---------------------------------------------------------------------------
// FUSED separable 7x7 avg pool: one kernel, LDS-staged.
// ---------------------------------------------------------------------------
__global__ __launch_bounds__(256) void pool_fused_kernel(const float* __restrict__ in,
                                                         float* __restrict__ out)
{
  __shared__ float raw[38][192];
  __shared__ float cs[32][192];
  int rt = blockIdx.x;
  int plane = blockIdx.y;
  int r0 = rt*32;
  int t = threadIdx.x;
  const float* src = in + (size_t)plane*HWq;
  for (int idx = t; idx < 38*192; idx += 256) {
    int lr = idx / 192, c = idx % 192;
    int gr = r0 - 3 + lr;
    raw[lr][c] = (gr >= 0 && gr < Hq) ? src[gr*Wq + c] : 0.f;
  }
  __syncthreads();
  for (int idx = t; idx < 32*192; idx += 256) {
    int lr = idx / 192, c = idx % 192;
    float s = 0.f;
#pragma unroll
    for (int dr = 0; dr < 7; dr++) s += raw[lr + dr][c];
    cs[lr][c] = s;
  }
  __syncthreads();
  float* dst = out + (size_t)plane*HWq + r0*Wq;
  for (int idx = t; idx < 32*192; idx += 256) {
    int lr = idx / 192, c = idx % 192;
    float s = 0.f;
#pragma unroll
    for (int dc = -3; dc <= 3; dc++) {
      int cc = c + dc;
      if (cc >= 0 && cc < Wq) s += cs[lr][cc];
    }
    dst[idx] = s * (1.f/49.f);
  }
}

// ---------------------------------------------------------------------------
// MERGED fused depthwise 19-tap + f16 HI/LO plane-major pack [b][sub16][px][8].
// Grid (144, 8, 4): z = branch*2 + b.
// ---------------------------------------------------------------------------
__global__ __launch_bounds__(256) void dwf_kernel(const float* __restrict__ x1,
                                                  const float* __restrict__ wEffH,
                                                  const float* __restrict__ bEffH,
                                                  const float* __restrict__ wBH,
                                                  const float* __restrict__ wEffV,
                                                  const float* __restrict__ bEffV,
                                                  const float* __restrict__ wBV,
                                                  unsigned short* __restrict__ packH,
                                                  unsigned short* __restrict__ packV)
{
  __shared__ float sW[8][19][20];
  int z = blockIdx.z;
  int br = z >> 1, b = z & 1;
  const float* wEff = br ? wEffV : wEffH;
  const float* bEff = br ? bEffV : bEffH;
  const float* wB   = br ? wBV   : wBH;
  unsigned short* pack = br ? packV : packH;
  int g8 = blockIdx.y;
  int t = threadIdx.x;
  int chb = g8*8;
  for (int i = t; i < 8*380; i += 256) {
    int ch8 = i / 380; int rem = i % 380;
    int row = rem / 20, jj = rem % 20;
    int ch = chb + ch8;
    float v;
    if (row < 18) v = wB[((size_t)ch*18 + row)*20 + jj];
    else v = (jj < 19) ? wEff[ch*19 + jj] : bEff[ch];
    sW[ch8][row][jj] = v;
  }
  __syncthreads();
  int p = blockIdx.x*256 + t;
  int r = p / Wq, c = p % Wq;
  float vals[8];
  if (br == 0) {
    int row = (c < 9) ? c : ((c >= Wq-9) ? (c - 174) : 18);
#pragma unroll
    for (int ch8 = 0; ch8 < 8; ch8++) {
      const float* src = x1 + (size_t)(b*Cq + chb + ch8)*HWq + r*Wq;
      float s = sW[ch8][row][19];
#pragma unroll
      for (int j = 0; j < 19; j++) {
        int idx = min(max(c + j - 9, 0), Wq-1);
        s += src[idx] * sW[ch8][row][j];
      }
      vals[ch8] = s;
    }
  } else {
    int row = (r < 9) ? r : ((r >= Hq-9) ? (r - 174) : 18);
#pragma unroll
    for (int ch8 = 0; ch8 < 8; ch8++) {
      const float* src = x1 + (size_t)(b*Cq + chb + ch8)*HWq + c;
      float s = sW[ch8][row][19];
#pragma unroll
      for (int j = 0; j < 19; j++) {
        int idx = min(max(r + j - 9, 0), Hq-1);
        s += src[idx*Wq] * sW[ch8][row][j];
      }
      vals[ch8] = s;
    }
  }
  unsigned int hi[4], lo[4];
#pragma unroll
  for (int q = 0; q < 4; q++) {
    __half h0 = __float2half(vals[2*q]);
    __half h1 = __float2half(vals[2*q+1]);
    __half l0 = __float2half(vals[2*q]   - __half2float(h0));
    __half l1 = __float2half(vals[2*q+1] - __half2float(h1));
    hi[q] = (unsigned int)h2us(h0) | ((unsigned int)h2us(h1) << 16);
    lo[q] = (unsigned int)h2us(l0) | ((unsigned int)h2us(l1) << 16);
  }
  *(uint4*)(pack + (((size_t)b*16 + g8)*HWq + p)*8)     = make_uint4(hi[0], hi[1], hi[2], hi[3]);
  *(uint4*)(pack + (((size_t)b*16 + 8 + g8)*HWq + p)*8) = make_uint4(lo[0], lo[1], lo[2], lo[3]);
}

// ---------------------------------------------------------------------------
// MERGED offset conv + tanh + cum (reads HI+LO -> near-f32 offsets).
// 1D grid 576, XCD-PARTITIONED.
// ---------------------------------------------------------------------------
__global__ __launch_bounds__(256) void off_cum_kernel(const unsigned short* __restrict__ fpH,
                                                      const unsigned short* __restrict__ fpV,
                                                      const float* __restrict__ wOffH,
                                                      const float* __restrict__ bOffH,
                                                      const float* __restrict__ wOffV,
                                                      const float* __restrict__ bOffV,
                                                      float* __restrict__ hcum,
                                                      float* __restrict__ vcum)
{
  const size_t HW8 = (size_t)HWq*8;
  int bid = blockIdx.x;                 // 0..575
  int xcd = bid & 7, lid = bid >> 3;    // lid 0..71
  int combo = xcd >> 1;                 // 0..3
  int br = combo >> 1, b = combo & 1;
  int pxblk = (xcd & 1)*72 + lid;       // 0..143
  const unsigned short* fp = br ? fpV : fpH;
  const float* wOff = br ? wOffV : wOffH;
  const float* bOff = br ? bOffV : bOffH;
  float* cum = br ? vcum : hcum;
  int p = pxblk*256 + threadIdx.x;
  int r = p / Wq, c = p % Wq;
  float tv[7];
#pragma unroll
  for (int m = 0; m < 7; m++) tv[m] = bOff[m];
  const unsigned short* fb = fp + (size_t)b*HWq*128;
  for (int tap = 0; tap < 9; tap++) {
    int dy = tap/3 - 1, dx = tap%3 - 1;
    int rr = r + dy, cc = c + dx;
    if (rr < 0 || rr >= Hq || cc < 0 || cc >= Wq) continue;
    const unsigned short* p0 = fb + ((size_t)rr*Wq + cc)*8;
    const float* wp = wOff + tap*512;
    for (int g = 0; g < 8; g++) {
      f16x8 hv = *(const f16x8*)(p0 + (size_t)g*HW8);
      f16x8 lv = *(const f16x8*)(p0 + (size_t)(8 + g)*HW8);
#pragma unroll
      for (int e = 0; e < 8; e++) {
        float fv = (float)hv[e] + (float)lv[e];
        const float* wr = wp + (g*8 + e)*8;
#pragma unroll
        for (int m = 0; m < 7; m++) tv[m] += fv * wr[m];
      }
    }
  }
#pragma unroll
  for (int m = 0; m < 7; m++) tv[m] = tanhf(tv[m]);
  float c0 = tv[0], c1 = tv[1] + tv[2], c2 = tv[2], c3 = 0.f;
  float c4 = tv[4], c5 = tv[4] + tv[5], c6 = tv[6];
  size_t bb = (size_t)b*7*HWq + p;
  cum[bb + 0*HWq] = c0; cum[bb + 1*HWq] = c1; cum[bb + 2*HWq] = c2;
  cum[bb + 3*HWq] = c3; cum[bb + 4*HWq] = c4; cum[bb + 5*HWq] = c5;
  cum[bb + 6*HWq] = c6;
}

// ---------------------------------------------------------------------------
// MERGED deformable sample + einsum via MFMA v3 (R25-validated, ~53 us):
// unified morph addressing, RUNTIME 7-tap loop, software pipeline
// ISSUE(k+1) || MFMA(k) || WRITE(k+1) with 2 LDS slots, depth 1.
// 32 px/wave, ch-split staging; BARRIER-FREE (intra-wave LDS, in-order DS).
// ---------------------------------------------------------------------------
__global__ __launch_bounds__(64, 3) void einsum_mfma_kernel(
    const unsigned short* __restrict__ fpH, const unsigned short* __restrict__ fpV,
    const float* __restrict__ cumH, const float* __restrict__ cumV,
    const unsigned short* __restrict__ wtpHp, const unsigned short* __restrict__ wtpVp,
    const float* __restrict__ dscbH, const float* __restrict__ dscbV,
    float* __restrict__ outH, float* __restrict__ outV,
    float* __restrict__ pstat)
{
  __shared__ __align__(16) unsigned short sA[2*32*64];  // 8 KB, 2 tap slots
  const size_t HW8 = (size_t)HWq*8;
  int morph = blockIdx.y;
  const unsigned short* fp  = morph ? fpV   : fpH;
  const float* cum          = morph ? cumV  : cumH;
  const unsigned short* wtp = morph ? wtpVp : wtpHp;
  const float* dsc_b        = morph ? dscbV : dscbH;
  float* out                = morph ? outV  : outH;
  int bid = blockIdx.x;                    // 0..2303
  int swz = (bid & 7)*288 + (bid >> 3);    // XCD-banded
  int b   = swz / 1152;
  int blk = swz % 1152;
  int l = threadIdx.x;                     // 0..63
  int l15 = l & 15, lg = l >> 4;
  int l7 = l & 7;
  int px5 = l & 31;                        // px within wave
  int chh = l >> 5;                        // channel half
  int p = blk*32 + px5;
  int r = p / Wq, c = p % Wq;

  // unified sampling params: morph0 fixes x (xi = c+k-3), samples along rows;
  // morph1 fixes y (yi = r+k-3), samples along cols. Both bounds are 192.
  int fixc   = morph ? r : c;              // coordinate that gets +k-3
  int vbase  = morph ? c : r;              // coordinate that gets cum offset
  int stride = morph ? 1 : Wq;

  f32x4 acc[2][4];
#pragma unroll
  for (int i = 0; i < 2; i++)
#pragma unroll
    for (int j = 0; j < 4; j++) acc[i][j] = (f32x4){0.f,0.f,0.f,0.f};

  const unsigned short* fb = fp + (size_t)b*HWq*128;

  f16x8 a0r[4], a1r[4];
  float w0, w1;
  bool oob;

#define ISSUE(KK)                                                           \
  {                                                                         \
    int fx = fixc + (KK) - 3;                                               \
    oob = (fx < 0 || fx >= 192);                                            \
    float vf = (float)vbase + cum[((size_t)(b*7 + (KK)))*HWq + p];          \
    float v0 = floorf(vf);                                                  \
    int v0q = (int)v0;                                                      \
    int v0i = min(max(v0q, 0), 191);                                        \
    int v1i = min(max(v0q + 1, 0), 191);                                    \
    float v0f = fminf(fmaxf(v0, 0.f), 192.f);                               \
    float v1f = fminf(fmaxf(v0 + 1.f, 0.f), 192.f);                         \
    w0 = v1f - vf; w1 = vf - v0f;                                           \
    int fixoff = morph ? fx*Wq : fx;                                        \
    const unsigned short* p0 = fb + (size_t)(fixoff + v0i*stride)*8;        \
    const unsigned short* p1 = fb + (size_t)(fixoff + v1i*stride)*8;        \
    if (!oob) {                                                             \
      _Pragma("unroll")                                                     \
      for (int gi = 0; gi < 4; gi++) {                                      \
        int g = chh*4 + gi;                                                 \
        a0r[gi] = *(const f16x8*)(p0 + (size_t)g*HW8);                      \
        a1r[gi] = *(const f16x8*)(p1 + (size_t)g*HW8);                      \
      }                                                                     \
    }                                                                       \
  }

#define WRITE(SLOT)                                                         \
  {                                                                         \
    unsigned short* myrow = sA + (size_t)((SLOT)*32 + px5)*64;              \
    if (oob) {                                                              \
      uint4 z = {0u,0u,0u,0u};                                              \
      _Pragma("unroll")                                                     \
      for (int gi = 0; gi < 4; gi++)                                        \
        *(uint4*)(myrow + (size_t)(((chh*4 + gi) ^ l7))*8) = z;             \
    } else {                                                                \
      _Pragma("unroll")                                                     \
      for (int gi = 0; gi < 4; gi++) {                                      \
        f16x8 sh;                                                           \
        _Pragma("unroll")                                                   \
        for (int e = 0; e < 8; e++) {                                       \
          float v = w0*(float)a0r[gi][e] + w1*(float)a1r[gi][e];            \
          sh[e] = (_Float16)v;                                              \
        }                                                                   \
        *(f16x8*)(myrow + (size_t)(((chh*4 + gi) ^ l7))*8) = sh;            \
      }                                                                     \
    }                                                                       \
  }

#define MFMA_TAP(KK, SLOT)                                                  \
  {                                                                         \
    _Pragma("unroll")                                                       \
    for (int kc = 0; kc < 2; kc++) {                                        \
      const unsigned short* wbase = wtp + (size_t)(((KK)*2 + kc)*2)*2048;   \
      f16x8 bh[4], bl[4];                                                   \
      _Pragma("unroll")                                                     \
      for (int tb = 0; tb < 4; tb++) {                                      \
        bh[tb] = *(const f16x8*)(wbase + (tb*16 + l15)*32 + lg*8);          \
        bl[tb] = *(const f16x8*)(wbase + 2048 + (tb*16 + l15)*32 + lg*8);   \
      }                                                                     \
      f16x8 ah[2];                                                          \
      _Pragma("unroll")                                                     \
      for (int ta = 0; ta < 2; ta++) {                                      \
        const unsigned short* rbase = sA + (size_t)((SLOT)*32 + ta*16 + l15)*64; \
        ah[ta] = *(const f16x8*)(rbase + (size_t)((kc*4 + lg) ^ l7)*8);     \
      }                                                                     \
      _Pragma("unroll")                                                     \
      for (int ta = 0; ta < 2; ta++)                                        \
        _Pragma("unroll")                                                   \
        for (int tb = 0; tb < 4; tb++) {                                    \
          acc[ta][tb] = __builtin_amdgcn_mfma_f32_16x16x32_f16(ah[ta], bh[tb], acc[ta][tb], 0, 0, 0); \
          acc[ta][tb] = __builtin_amdgcn_mfma_f32_16x16x32_f16(ah[ta], bl[tb], acc[ta][tb], 0, 0, 0); \
        }                                                                   \
    }                                                                       \
  }

  ISSUE(0);
  WRITE(0);
#pragma unroll 1
  for (int k = 0; k < 7; k++) {
    int slot = k & 1;
    if (k < 6) ISSUE(k+1);          // next-tap loads in flight across MFMA
    MFMA_TAP(k, slot);              // lgkm waits on WRITE(k)
    if (k < 6) WRITE((k+1) & 1);    // vmcnt wait + lerp + ds_write
  }
#undef ISSUE
#undef WRITE
#undef MFMA_TAP

  int pbase = blk*32;
#pragma unroll
  for (int tb = 0; tb < 4; tb++) {
    int oc = tb*16 + l15;
    float bias = dsc_b[oc];
    float* dst = out + (size_t)(b*64 + oc)*HWq + pbase;
    float s = 0.f, ss = 0.f;
#pragma unroll
    for (int ta = 0; ta < 2; ta++) {
      f32x4 v = acc[ta][tb];
      float v0 = v[0]+bias, v1 = v[1]+bias, v2 = v[2]+bias, v3 = v[3]+bias;
      *(float4*)(dst + ta*16 + lg*4) = make_float4(v0, v1, v2, v3);
      s  += v0 + v1 + v2 + v3;
      ss += v0*v0 + v1*v1 + v2*v2 + v3*v3;
    }
    s  += __shfl_xor(s, 16);
    s  += __shfl_xor(s, 32);
    ss += __shfl_xor(ss, 16);
    ss += __shfl_xor(ss, 32);
    if (lg == 0) {
      float* pp = pstat + ((size_t)(morph*2304 + swz))*128 + oc*2;
      pp[0] = s; pp[1] = ss;
    }
  }
}

// ---------------------------------------------------------------------------
// GN partial reduce: grid 256 (one block per (buf,b,ch)), reads pstat.
// ---------------------------------------------------------------------------
__global__ __launch_bounds__(256) void gnred_kernel(const float* __restrict__ pstat,
                                                    float* __restrict__ stats)
{
  int combo = blockIdx.x;           // buf*128 + b*64 + ch
  int buf = combo >> 7;
  int rem = combo & 127;
  int b = rem >> 6, ch = rem & 63;
  int t = threadIdx.x;
  float s = 0.f, ss = 0.f;
  for (int q = t; q < 1152; q += 256) {
    const float* pp = pstat + ((size_t)(buf*2304 + b*1152 + q))*128 + ch*2;
    s += pp[0]; ss += pp[1];
  }
  __shared__ float red[2][4];
  for (int off = 32; off; off >>= 1) {
    s  += __shfl_down(s, off);
    ss += __shfl_down(ss, off);
  }
  if ((t & 63) == 0) { red[0][t >> 6] = s; red[1][t >> 6] = ss; }
  __syncthreads();
  if (t == 0) {
    s  = red[0][0] + red[0][1] + red[0][2] + red[0][3];
    ss = red[1][0] + red[1][1] + red[1][2] + red[1][3];
    stats[combo*2 + 0] = s;
    stats[combo*2 + 1] = ss;
  }
}

__global__ __launch_bounds__(256) void gnfinal_kernel(const float* __restrict__ stats,
                                                      const float* __restrict__ h_gn_g, const float* __restrict__ h_gn_b,
                                                      const float* __restrict__ v_gn_g, const float* __restrict__ v_gn_b,
                                                      float* __restrict__ gnAB)
{
  int t = threadIdx.x;
  int buf = t >> 7, ch = t & 63;
  int base = t & ~3;
  float sum = 0.f, ss = 0.f;
#pragma unroll
  for (int q = 0; q < 4; q++) { sum += stats[(base+q)*2]; ss += stats[(base+q)*2 + 1]; }
  const float n = 4.f * HWq;
  float mean = sum / n;
  float var = ss / n - mean*mean;
  float gg = (buf ? v_gn_g : h_gn_g)[ch];
  float bb = (buf ? v_gn_b : h_gn_b)[ch];
  float A = gg / sqrtf(var + 1e-5f);
  gnAB[t*2 + 0] = A;
  gnAB[t*2 + 1] = bb - mean*A;
}

// ---------------------------------------------------------------------------
// FUSED: comb = relu(GN(h)) + relu(GN(v)) + x1 inline, then 1x1 conv + SiLU
// ---------------------------------------------------------------------------
__global__ __launch_bounds__(256) void final2_kernel(const float* __restrict__ hbuf,
                                                     const float* __restrict__ vbuf,
                                                     const float* __restrict__ x1,
                                                     const float* __restrict__ gnAB,
                                                     const float* __restrict__ lwT,
                                                     const float* __restrict__ lbO,
                                                     float* __restrict__ out)
{
  int b = blockIdx.y;
  int p = blockIdx.x*256 + threadIdx.x;
  float acc[64];
#pragma unroll
  for (int o = 0; o < 64; o++) acc[o] = 0.f;
  for (int i = 0; i < 64; i++) {
    size_t off = (size_t)(b*64 + i)*HWq + p;
    int plane = b*64 + i;
    int ih = plane*2;
    int iv = (128 + plane)*2;
    float hv = fmaxf(hbuf[off]*gnAB[ih] + gnAB[ih+1], 0.f);
    float vv = fmaxf(vbuf[off]*gnAB[iv] + gnAB[iv+1], 0.f);
    float cv = hv + vv + x1[off];
    const float* wr = lwT + i*64;
#pragma unroll
    for (int o = 0; o < 64; o++) acc[o] += cv * wr[o];
  }
  float* dst = out + (size_t)b*Cq*HWq + p;
#pragma unroll
  for (int o = 0; o < 64; o++) {
    float yv = acc[o] + lbO[o];
    dst[(size_t)o*HWq] = yv / (1.f + expf(-yv));
  }
}

// ---------------------------------------------------------------------------
extern "C" void kernel_launch(void* const* d_in, const int* in_sizes, int n_in,
                              void* d_out, int out_size, void* d_ws, size_t ws_size,
                              hipStream_t stream)
{
  const float* x       = (const float*)d_in[0];
  const float* w_first = (const float*)d_in[1];
  float* ws = (float*)d_ws;

  float* bufA = ws;            // conv7 out -> h-einsum-out
  float* bufB = ws + Nq;       // v-einsum-out
  float* x1   = ws + 2*Nq;
  float* h_ds = ws + 3*Nq;     // xpack -> fpackH
  float* v_ds = ws + 4*Nq;     // fpackV
  size_t off = 5*Nq;
  float* hcum  = ws + off; off += (size_t)Bq*7*HWq;
  float* vcum  = ws + off; off += (size_t)Bq*7*HWq;
  float* wEffH = ws + off; off += 64*19;
  float* bEffH = ws + off; off += 64;
  float* wEffV = ws + off; off += 64*19;
  float* bEffV = ws + off; off += 64;
  float* wtH   = ws + off; off += 64*64*7;   // holds wtpH f16 pack
  float* wtV   = ws + off; off += 64*64*7;   // holds wtpV f16 pack
  float* wOffH = ws + off; off += 9*64*8;
  float* bOffH = ws + off; off += 8;
  float* wOffV = ws + off; off += 9*64*8;
  float* bOffV = ws + off; off += 8;
  float* lwT   = ws + off; off += 64*64;
  float* lbO   = ws + off; off += 64;
  float* stats = ws + off; off += 512;
  float* gnAB  = ws + off; off += 512;
  float* wB    = ws + off; off += 2*64*18*20;
  float* pstat = ws + off; off += (size_t)2*2304*128;
  unsigned short* wpack = (unsigned short*)(ws + off); off += 2*49*2*64*32/2 + 16;
  unsigned short* xpack  = (unsigned short*)h_ds;
  unsigned short* fpackH = (unsigned short*)h_ds;
  unsigned short* fpackV = (unsigned short*)v_ds;
  unsigned short* wtpH = (unsigned short*)wtH;
  unsigned short* wtpV = (unsigned short*)wtV;

  prep_all_kernel<<<dim3(74), dim3(256), 0, stream>>>(
      (const float*)d_in[2],  (const float*)d_in[3],  (const float*)d_in[4],  (const float*)d_in[5],
      (const float*)d_in[6],  (const float*)d_in[7],
      (const float*)d_in[8],  (const float*)d_in[9],  (const float*)d_in[10], (const float*)d_in[11],
      (const float*)d_in[12], (const float*)d_in[13],
      (const float*)d_in[14], (const float*)d_in[15], (const float*)d_in[16], (const float*)d_in[17],
      (const float*)d_in[18], (const float*)d_in[19],
      (const float*)d_in[24], (const float*)d_in[25], (const float*)d_in[26], (const float*)d_in[27],
      (const float*)d_in[28], (const float*)d_in[29],
      (const float*)d_in[34], (const float*)d_in[35], (const float*)d_in[36], (const float*)d_in[37],
      (const float*)d_in[38],
      w_first, (const float*)d_in[20], (const float*)d_in[30],
      wEffH, bEffH, wEffV, bEffV, wOffH, bOffH, wOffV, bOffV, lwT, lbO, wB,
      wtpH, wtpV, wpack);

  tof16_pack_kernel<<<dim3(Hq, Bq), dim3(192), 0, stream>>>(x, xpack);
  conv7_mfma_kernel<<<dim3(4, 96, 2), dim3(256), 0, stream>>>(xpack, wpack, bufA);

  pool_fused_kernel<<<dim3(6, 128), dim3(256), 0, stream>>>(bufA, x1);

  dwf_kernel<<<dim3(144, 8, 4), dim3(256), 0, stream>>>(x1, wEffH, bEffH, wB,
      wEffV, bEffV, wB + 64*18*20, fpackH, fpackV);

  off_cum_kernel<<<dim3(576), dim3(256), 0, stream>>>(fpackH, fpackV,
      wOffH, bOffH, wOffV, bOffV, hcum, vcum);

  einsum_mfma_kernel<<<dim3(2304, 2), dim3(64), 0, stream>>>(fpackH, fpackV,
      hcum, vcum, wtpH, wtpV, (const float*)d_in[21], (const float*)d_in[31], bufA, bufB, pstat);

  gnred_kernel<<<dim3(256), dim3(256), 0, stream>>>(pstat, stats);
  gnfinal_kernel<<<dim3(1), dim3(256), 0, stream>>>(stats,
      (const float*)d_in[22], (const float*)d_in[23],
      (const float*)d_in[32], (const float*)d_in[33], gnAB);

  final2_kernel<<<dim3(144, 2), dim3(256), 0, stream>>>(bufA, bufB, x1, gnAB, lwT, lbO, (float*)d_out);
}

// Round 28
// 283.451 us; speedup vs baseline: 1.0785x; 1.0742x over previous
//
#include <hip/hip_runtime.h>
#include <hip/hip_bf16.h>
#include <hip/hip_fp16.h>
#include <math.h>

#define Bq 2
#define Cq 64
#define Hq 192
#define Wq 192
#define HWq (Hq*Wq)            // 36864
#define Nq ((size_t)Bq*Cq*HWq) // 4718592

typedef __attribute__((ext_vector_type(8))) _Float16 f16x8;
typedef __attribute__((ext_vector_type(4))) float f32x4;

__device__ inline unsigned short h2us(__half h) {
  union { __half h; unsigned short u; } v; v.h = h; return v.u;
}

// ---------------------------------------------------------------------------
// MERGED prep: block 0 = small folds + offset B-pack; blocks 1-9 = border;
// blocks 10-73 = big packs.
// ---------------------------------------------------------------------------
__global__ __launch_bounds__(256) void prep_all_kernel(
    const float* hc1_w, const float* hc1_b, const float* hc2_w, const float* hc2_b,
    const float* hc3_w, const float* hc3_b,
    const float* vc1_w, const float* vc1_b, const float* vc2_w, const float* vc2_b,
    const float* vc3_w, const float* vc3_b,
    const float* h_off_w, const float* h_off_b, const float* h_bn_g, const float* h_bn_b,
    const float* h_bn_m, const float* h_bn_v,
    const float* v_off_w, const float* v_off_b, const float* v_bn_g, const float* v_bn_b,
    const float* v_bn_m, const float* v_bn_v,
    const float* last_w, const float* last_g, const float* last_b, const float* last_m,
    const float* last_v,
    const float* __restrict__ w_first,
    const float* __restrict__ h_dsc_w, const float* __restrict__ v_dsc_w,
    float* wEffH, float* bEffH, float* wEffV, float* bEffV,
    unsigned short* __restrict__ wOpH, unsigned short* __restrict__ wOpV,
    float* bOffH, float* bOffV,
    float* lwT, float* lbO, float* wB,
    unsigned short* __restrict__ wtpH, unsigned short* __restrict__ wtpV,
    unsigned short* __restrict__ wpack)
{
  int bid = blockIdx.x;
  int t = threadIdx.x;
  if (bid == 0) {
    // ---- small folds ------------------------------------------------------
    if (t < 128) {
      int ch = t & 63;
      bool ish = t < 64;
      const float* w1p = (ish ? hc1_w : vc1_w) + ch*9;
      const float* w2p = (ish ? hc2_w : vc2_w) + ch*7;
      const float* w3p = (ish ? hc3_w : vc3_w) + ch*5;
      float w1r[9], w2r[7], w3r[5];
#pragma unroll
      for (int j = 0; j < 9; j++) w1r[j] = w1p[j];
#pragma unroll
      for (int k = 0; k < 7; k++) w2r[k] = w2p[k];
#pragma unroll
      for (int m = 0; m < 5; m++) w3r[m] = w3p[m];
      float t15[15];
#pragma unroll
      for (int s = 0; s < 15; s++) {
        float a = 0.f;
#pragma unroll
        for (int j = 0; j < 9; j++) { int k2 = s - j; if (k2 >= 0 && k2 < 7) a += w1r[j]*w2r[k2]; }
        t15[s] = a;
      }
      float* we = (ish ? wEffH : wEffV) + ch*19;
#pragma unroll
      for (int s = 0; s < 19; s++) {
        float a = 0.f;
#pragma unroll
        for (int j = 0; j < 15; j++) { int k3 = s - j; if (k3 >= 0 && k3 < 5) a += t15[j]*w3r[k3]; }
        we[s] = a;
      }
      float S2 = 0.f, S3 = 0.f;
#pragma unroll
      for (int j = 0; j < 7; j++) S2 += w2r[j];
#pragma unroll
      for (int j = 0; j < 5; j++) S3 += w3r[j];
      float b1 = (ish ? hc1_b : vc1_b)[ch];
      float b2 = (ish ? hc2_b : vc2_b)[ch];
      float b3 = (ish ? hc3_b : vc3_b)[ch];
      (ish ? bEffH : bEffV)[ch] = b1*S2*S3 + b2*S3 + b3;
    }
    // ---- offset-conv MFMA B-pack [tap][kc][hl][n16][k32] f16 --------------
    for (int idx = t; idx < 9*2*2*16*32; idx += 256) {
      int k  = idx & 31;
      int n  = (idx >> 5) & 15;
      int hl = (idx >> 9) & 1;
      int kc = (idx >> 10) & 1;
      int tap = idx >> 11;
      int ch = kc*32 + k;
      float wh = 0.f, wv2 = 0.f;
      if (n < 7) {
        float invh = h_bn_g[n] / sqrtf(h_bn_v[n] + 1e-5f);
        wh = h_off_w[((size_t)n*64 + ch)*9 + tap] * invh;
        float invv = v_bn_g[7+n] / sqrtf(v_bn_v[7+n] + 1e-5f);
        wv2 = v_off_w[((size_t)(7+n)*64 + ch)*9 + tap] * invv;
      }
      _Float16 hh = (_Float16)wh;
      _Float16 hv = (_Float16)wv2;
      unsigned short uh, uv;
      if (!hl) { uh = *(unsigned short*)&hh; uv = *(unsigned short*)&hv; }
      else {
        _Float16 lh = (_Float16)(wh - (float)hh);
        _Float16 lv = (_Float16)(wv2 - (float)hv);
        uh = *(unsigned short*)&lh; uv = *(unsigned short*)&lv;
      }
      wOpH[idx] = uh; wOpV[idx] = uv;
    }
    if (t < 7) {
      float invh = h_bn_g[t] / sqrtf(h_bn_v[t] + 1e-5f);
      bOffH[t] = h_off_b[t]*invh + h_bn_b[t] - h_bn_m[t]*invh;
      float invv = v_bn_g[7+t] / sqrtf(v_bn_v[7+t] + 1e-5f);
      bOffV[t] = v_off_b[7+t]*invv + v_bn_b[7+t] - v_bn_m[7+t]*invv;
    }
    for (int idx = t; idx < 4096; idx += 256) {
      int o = idx % 64; int i = idx / 64;
      float inv = last_g[o] / sqrtf(last_v[o] + 1e-3f);
      lwT[i*64 + o] = last_w[o*64 + i] * inv;
    }
    if (t < 64) {
      float inv = last_g[t] / sqrtf(last_v[t] + 1e-3f);
      lbO[t] = last_b[t] - last_m[t]*inv;
    }
  } else if (bid <= 9) {
    // ---- border composed weights ------------------------------------------
    int tid = (bid - 1)*256 + t;
    if (tid >= 2*64*18) return;
    int cls = tid % 18;
    int ch  = (tid / 18) % 64;
    int br  = tid / (18*64);
    int c = (cls < 9) ? cls : cls + 174;
    const float* w1p = (br==0 ? hc1_w : vc1_w) + ch*9;
    const float* w2p = (br==0 ? hc2_w : vc2_w) + ch*7;
    const float* w3p = (br==0 ? hc3_w : vc3_w) + ch*5;
    float b1 = (br==0 ? hc1_b : vc1_b)[ch];
    float b2 = (br==0 ? hc2_b : vc2_b)[ch];
    float b3 = (br==0 ? hc3_b : vc3_b)[ch];
    float w1r[9], w2r[7], w3r[5];
#pragma unroll
    for (int j = 0; j < 9; j++) w1r[j] = w1p[j];
#pragma unroll
    for (int k = 0; k < 7; k++) w2r[k] = w2p[k];
#pragma unroll
    for (int m = 0; m < 5; m++) w3r[m] = w3p[m];
    float acc[19];
#pragma unroll
    for (int s = 0; s < 19; s++) acc[s] = 0.f;
    float bacc = b3;
#pragma unroll
    for (int m = 0; m < 5; m++) {
      int d = c + m - 2;
      bool dok = (d >= 0 && d < Wq);
      float s2b = b2;
#pragma unroll
      for (int k = 0; k < 7; k++) {
        int e = d + k - 3;
        bool eok = (e >= 0 && e < Wq);
        if (eok) s2b += w2r[k] * b1;
        float wmk = w3r[m] * w2r[k];
#pragma unroll
        for (int j = 0; j < 9; j++) {
          int fd = e + j - 4;
          bool fok = (fd >= 0 && fd < Wq);
          float contrib = (dok && eok && fok) ? wmk * w1r[j] : 0.f;
          acc[m + k + j] += contrib;
        }
      }
      if (dok) bacc += w3r[m] * s2b;
    }
    float* dst = wB + ((size_t)(br*64 + ch)*18 + cls)*20;
#pragma unroll
    for (int s = 0; s < 19; s++) dst[s] = acc[s];
    dst[19] = bacc;
  } else {
    // ---- big packs --------------------------------------------------------
    int tid = (bid - 10)*256 + t;
    int nthr = 64*256;
    for (int idx = tid; idx < 7*2*2*64*32; idx += nthr) {
      int ch32 = idx & 31;
      int oc   = (idx >> 5) & 63;
      int hl   = (idx >> 11) & 1;
      int kc   = (idx >> 12) & 1;
      int tap  = idx >> 13;
      int i = kc*32 + ch32;
      float vh = h_dsc_w[oc*448 + i*7 + tap];
      float vv = v_dsc_w[oc*448 + i*7 + tap];
      _Float16 hh = (_Float16)vh;
      _Float16 hv = (_Float16)vv;
      unsigned short uh, uv;
      if (!hl) { uh = *(unsigned short*)&hh; uv = *(unsigned short*)&hv; }
      else {
        _Float16 lh = (_Float16)(vh - (float)hh);
        _Float16 lv = (_Float16)(vv - (float)hv);
        uh = *(unsigned short*)&lh; uv = *(unsigned short*)&lv;
      }
      wtpH[idx] = uh; wtpV[idx] = uv;
    }
    for (int e = tid; e < 2*49*2*64*32; e += nthr) {
      int ch  = e & 31;
      int oc  = (e >> 5) & 63;
      int hl  = (e >> 11) & 1;
      int rest = e >> 12;
      int tap = rest % 49;
      int h   = rest / 49;
      float wv = w_first[((size_t)oc*64 + h*32 + ch)*49 + tap];
      __half hh = __float2half(wv);
      unsigned short us;
      if (!hl) us = h2us(hh);
      else { float rr = wv - __half2float(hh); us = h2us(__float2half(rr)); }
      wpack[e] = us;
    }
  }
}

// ---------------------------------------------------------------------------
// x (NCHW f32) -> xpack single f16: [b][r][c][64]
// ---------------------------------------------------------------------------
__global__ __launch_bounds__(192) void tof16_pack_kernel(const float* __restrict__ x,
                                                         unsigned short* __restrict__ xpack)
{
  __shared__ unsigned int s[192*64];
  int r = blockIdx.x, b = blockIdx.y;
  int t = threadIdx.x;
  for (int ch = 0; ch < 64; ch++) {
    float v = x[((size_t)(b*64+ch)*Hq + r)*Wq + t];
    _Float16 hh = (_Float16)v;
    s[t*64 + (ch ^ (t & 31))] = (unsigned int)*(unsigned short*)&hh;
  }
  __syncthreads();
  unsigned short* dst = xpack + ((size_t)b*Hq + r)*Wq*64;
  for (int i = 0; i < 8; i++) {
    int gidx = i*192 + t;
    int c = gidx >> 3, g = gidx & 7;
    unsigned short tmp[8];
#pragma unroll
    for (int j = 0; j < 8; j++) {
      int ch = g*8 + j;
      tmp[j] = (unsigned short)s[c*64 + (ch ^ (c & 31))];
    }
    uint4 v;
    v.x = (unsigned int)tmp[0] | ((unsigned int)tmp[1] << 16);
    v.y = (unsigned int)tmp[2] | ((unsigned int)tmp[3] << 16);
    v.z = (unsigned int)tmp[4] | ((unsigned int)tmp[5] << 16);
    v.w = (unsigned int)tmp[6] | ((unsigned int)tmp[7] << 16);
    *(uint4*)(dst + (size_t)gidx*8) = v;
  }
}

// ---------------------------------------------------------------------------
// 7x7 conv via MFMA, 2-pass (x single f16, w hi/lo exact) — R23 validated.
// ---------------------------------------------------------------------------
__global__ __launch_bounds__(256) void conv7_mfma_kernel(
    const unsigned short* __restrict__ xpack,   // [b][r][c][64] f16
    const unsigned short* __restrict__ wpack,   // [h][tap][hl][oc][32] f16
    float* __restrict__ out)
{
  __shared__ __align__(16) unsigned short sA[8*54*32];   // 27648 B
  int ct = blockIdx.x;          // 0..3
  int rt = blockIdx.y;          // 0..95
  int b  = blockIdx.z;
  int r0 = rt*2, c0 = ct*48;
  int t = threadIdx.x;
  int wv = t >> 6;              // wave -> oc quarter
  int l  = t & 63;
  int l15 = l & 15, lg = l >> 4;
  int oc = wv*16 + l15;

  f32x4 acc[2][3];
#pragma unroll
  for (int i = 0; i < 2; i++)
#pragma unroll
    for (int j = 0; j < 3; j++) acc[i][j] = (f32x4){0.f,0.f,0.f,0.f};

  for (int h = 0; h < 2; h++) {
    __syncthreads();
    for (int idx = t; idx < 8*54*4; idx += 256) {
      int g = idx & 3, pix = idx >> 2;
      int row = pix / 54, col = pix % 54;
      int gr = r0 - 3 + row, gc = c0 - 3 + col;
      uint4 v = {0u,0u,0u,0u};
      if (gr >= 0 && gr < Hq && gc >= 0 && gc < Wq)
        v = *(const uint4*)(xpack + (((size_t)b*Hq + gr)*Wq + gc)*64 + (h*4 + g)*8);
      ((uint4*)sA)[(row*54 + col)*4 + (g ^ ((col >> 1) & 3))] = v;
    }
    __syncthreads();
    const unsigned short* wb = wpack + (size_t)h*49*4096;
#pragma unroll 7
    for (int tap = 0; tap < 49; tap++) {
      int dy = tap / 7, dx = tap % 7;
      f16x8 bh = *(const f16x8*)(wb + (size_t)tap*4096 +        oc*32 + lg*8);
      f16x8 bl = *(const f16x8*)(wb + (size_t)tap*4096 + 2048 + oc*32 + lg*8);
#pragma unroll
      for (int rw = 0; rw < 2; rw++) {
        int arow = rw + dy;
        f16x8 a[3];
#pragma unroll
        for (int tc = 0; tc < 3; tc++) {
          int col = tc*16 + l15 + dx;
          a[tc] = *(const f16x8*)((const uint4*)sA + (arow*54 + col)*4 + (lg ^ ((col >> 1) & 3)));
        }
#pragma unroll
        for (int tc = 0; tc < 3; tc++) {
          acc[rw][tc] = __builtin_amdgcn_mfma_f32_16x16x32_f16(a[tc], bh, acc[rw][tc], 0, 0, 0);
          acc[rw][tc] = __builtin_amdgcn_mfma_f32_16x16x32_f16(a[tc], bl, acc[rw][tc], 0, 0, 0);
        }
      }
    }
  }
#pragma unroll
  for (int rw = 0; rw < 2; rw++) {
    float* dst = out + ((size_t)(b*64 + oc)*Hq + (r0 + rw))*Wq + c0;
#pragma unroll
    for (int tc = 0; tc < 3; tc++) {
      f32x4 v = acc[rw][tc];
      *(float4*)(dst + tc*16 + lg*4) = make_float4(v[0], v[1], v[2], v[3]);
    }
  }
}

// ---------------------------------------------------------------------------
// FUSED separable 7x7 avg pool: one kernel, LDS-staged.
// ---------------------------------------------------------------------------
__global__ __launch_bounds__(256) void pool_fused_kernel(const float* __restrict__ in,
                                                         float* __restrict__ out)
{
  __shared__ float raw[38][192];
  __shared__ float cs[32][192];
  int rt = blockIdx.x;
  int plane = blockIdx.y;
  int r0 = rt*32;
  int t = threadIdx.x;
  const float* src = in + (size_t)plane*HWq;
  for (int idx = t; idx < 38*192; idx += 256) {
    int lr = idx / 192, c = idx % 192;
    int gr = r0 - 3 + lr;
    raw[lr][c] = (gr >= 0 && gr < Hq) ? src[gr*Wq + c] : 0.f;
  }
  __syncthreads();
  for (int idx = t; idx < 32*192; idx += 256) {
    int lr = idx / 192, c = idx % 192;
    float s = 0.f;
#pragma unroll
    for (int dr = 0; dr < 7; dr++) s += raw[lr + dr][c];
    cs[lr][c] = s;
  }
  __syncthreads();
  float* dst = out + (size_t)plane*HWq + r0*Wq;
  for (int idx = t; idx < 32*192; idx += 256) {
    int lr = idx / 192, c = idx % 192;
    float s = 0.f;
#pragma unroll
    for (int dc = -3; dc <= 3; dc++) {
      int cc = c + dc;
      if (cc >= 0 && cc < Wq) s += cs[lr][cc];
    }
    dst[idx] = s * (1.f/49.f);
  }
}

// ---------------------------------------------------------------------------
// MERGED fused depthwise 19-tap + f16 HI/LO plane-major pack [b][sub16][px][8].
// Grid (144, 8, 4): z = branch*2 + b.
// ---------------------------------------------------------------------------
__global__ __launch_bounds__(256) void dwf_kernel(const float* __restrict__ x1,
                                                  const float* __restrict__ wEffH,
                                                  const float* __restrict__ bEffH,
                                                  const float* __restrict__ wBH,
                                                  const float* __restrict__ wEffV,
                                                  const float* __restrict__ bEffV,
                                                  const float* __restrict__ wBV,
                                                  unsigned short* __restrict__ packH,
                                                  unsigned short* __restrict__ packV)
{
  __shared__ float sW[8][19][20];
  int z = blockIdx.z;
  int br = z >> 1, b = z & 1;
  const float* wEff = br ? wEffV : wEffH;
  const float* bEff = br ? bEffV : bEffH;
  const float* wB   = br ? wBV   : wBH;
  unsigned short* pack = br ? packV : packH;
  int g8 = blockIdx.y;
  int t = threadIdx.x;
  int chb = g8*8;
  for (int i = t; i < 8*380; i += 256) {
    int ch8 = i / 380; int rem = i % 380;
    int row = rem / 20, jj = rem % 20;
    int ch = chb + ch8;
    float v;
    if (row < 18) v = wB[((size_t)ch*18 + row)*20 + jj];
    else v = (jj < 19) ? wEff[ch*19 + jj] : bEff[ch];
    sW[ch8][row][jj] = v;
  }
  __syncthreads();
  int p = blockIdx.x*256 + t;
  int r = p / Wq, c = p % Wq;
  float vals[8];
  if (br == 0) {
    int row = (c < 9) ? c : ((c >= Wq-9) ? (c - 174) : 18);
#pragma unroll
    for (int ch8 = 0; ch8 < 8; ch8++) {
      const float* src = x1 + (size_t)(b*Cq + chb + ch8)*HWq + r*Wq;
      float s = sW[ch8][row][19];
#pragma unroll
      for (int j = 0; j < 19; j++) {
        int idx = min(max(c + j - 9, 0), Wq-1);
        s += src[idx] * sW[ch8][row][j];
      }
      vals[ch8] = s;
    }
  } else {
    int row = (r < 9) ? r : ((r >= Hq-9) ? (r - 174) : 18);
#pragma unroll
    for (int ch8 = 0; ch8 < 8; ch8++) {
      const float* src = x1 + (size_t)(b*Cq + chb + ch8)*HWq + c;
      float s = sW[ch8][row][19];
#pragma unroll
      for (int j = 0; j < 19; j++) {
        int idx = min(max(r + j - 9, 0), Hq-1);
        s += src[idx*Wq] * sW[ch8][row][j];
      }
      vals[ch8] = s;
    }
  }
  unsigned int hi[4], lo[4];
#pragma unroll
  for (int q = 0; q < 4; q++) {
    __half h0 = __float2half(vals[2*q]);
    __half h1 = __float2half(vals[2*q+1]);
    __half l0 = __float2half(vals[2*q]   - __half2float(h0));
    __half l1 = __float2half(vals[2*q+1] - __half2float(h1));
    hi[q] = (unsigned int)h2us(h0) | ((unsigned int)h2us(h1) << 16);
    lo[q] = (unsigned int)h2us(l0) | ((unsigned int)h2us(l1) << 16);
  }
  *(uint4*)(pack + (((size_t)b*16 + g8)*HWq + p)*8)     = make_uint4(hi[0], hi[1], hi[2], hi[3]);
  *(uint4*)(pack + (((size_t)b*16 + 8 + g8)*HWq + p)*8) = make_uint4(lo[0], lo[1], lo[2], lo[3]);
}

// ---------------------------------------------------------------------------
// OFFSET conv + tanh + cum via MFMA (3-pass hi/lo: Ah*Bh + Ah*Bl + Al*Bh).
// Wave = 32 px (2 M-tiles); A direct from fpack (coalesced, no LDS);
// B = packed weights [tap][kc][hl][n16][k32] (7 outputs, zero-padded).
// Grid 4608 x 64thr, XCD-partitioned: combo = (bid&7)>>1.
// ---------------------------------------------------------------------------
__global__ __launch_bounds__(64, 4) void off_cum_kernel(
    const unsigned short* __restrict__ fpH, const unsigned short* __restrict__ fpV,
    const unsigned short* __restrict__ wOpH, const unsigned short* __restrict__ wOpV,
    const float* __restrict__ bOffH, const float* __restrict__ bOffV,
    float* __restrict__ hcum, float* __restrict__ vcum)
{
  const size_t HW8 = (size_t)HWq*8;
  int bid = blockIdx.x;                 // 0..4607
  int xcd = bid & 7, lid = bid >> 3;    // lid 0..575
  int combo = xcd >> 1;                 // 0..3
  int br = combo >> 1, b = combo & 1;
  int wv = (xcd & 1)*576 + lid;         // 0..1151 wave index within combo
  const unsigned short* fp  = br ? fpV  : fpH;
  const unsigned short* wOp = br ? wOpV : wOpH;
  const float* bOff = br ? bOffV : bOffH;
  float* cum = br ? vcum : hcum;
  int pb = wv*32;
  int l = threadIdx.x;
  int l15 = l & 15, lg = l >> 4;
  const unsigned short* fb = fp + (size_t)b*HWq*128;

  int r0[2], c0[2];
#pragma unroll
  for (int ta = 0; ta < 2; ta++) {
    int px = pb + ta*16 + l15;
    r0[ta] = px / Wq; c0[ta] = px % Wq;
  }

  f32x4 acc[2];
  acc[0] = (f32x4){0.f,0.f,0.f,0.f};
  acc[1] = (f32x4){0.f,0.f,0.f,0.f};

#pragma unroll 1
  for (int tap = 0; tap < 9; tap++) {
    int dy = tap/3 - 1, dx = tap%3 - 1;
    f16x8 Ahi[2][2], Alo[2][2];
#pragma unroll
    for (int ta = 0; ta < 2; ta++) {
      int rr = r0[ta] + dy, cc = c0[ta] + dx;
      bool ok = (rr >= 0 && rr < Hq && cc >= 0 && cc < Wq);
      if (ok) {
        size_t base = (size_t)(rr*Wq + cc)*8;
#pragma unroll
        for (int kc = 0; kc < 2; kc++) {
          int g = kc*4 + lg;
          const unsigned short* p0 = fb + (size_t)g*HW8 + base;
          Ahi[ta][kc] = *(const f16x8*)p0;
          Alo[ta][kc] = *(const f16x8*)(p0 + (size_t)8*HW8);
        }
      } else {
        uint4 z = {0u,0u,0u,0u};
#pragma unroll
        for (int kc = 0; kc < 2; kc++) {
          *(uint4*)&Ahi[ta][kc] = z;
          *(uint4*)&Alo[ta][kc] = z;
        }
      }
    }
    f16x8 Bh[2], Bl[2];
#pragma unroll
    for (int kc = 0; kc < 2; kc++) {
      const unsigned short* wb = wOp + (size_t)((tap*2 + kc)*2)*512 + l15*32 + lg*8;
      Bh[kc] = *(const f16x8*)wb;
      Bl[kc] = *(const f16x8*)(wb + 512);
    }
#pragma unroll
    for (int ta = 0; ta < 2; ta++)
#pragma unroll
      for (int kc = 0; kc < 2; kc++) {
        acc[ta] = __builtin_amdgcn_mfma_f32_16x16x32_f16(Ahi[ta][kc], Bh[kc], acc[ta], 0, 0, 0);
        acc[ta] = __builtin_amdgcn_mfma_f32_16x16x32_f16(Ahi[ta][kc], Bl[kc], acc[ta], 0, 0, 0);
        acc[ta] = __builtin_amdgcn_mfma_f32_16x16x32_f16(Alo[ta][kc], Bh[kc], acc[ta], 0, 0, 0);
      }
  }

  float bias = (l15 < 7) ? bOff[l15] : 0.f;
  size_t cb = (size_t)b*7*HWq;
  int src_up = (l & 48) | ((l15 + 1) & 15);
  int src_dn = (l & 48) | ((l15 - 1) & 15);
#pragma unroll
  for (int ta = 0; ta < 2; ta++) {
    int pxb = pb + ta*16 + lg*4;
#pragma unroll
    for (int j = 0; j < 4; j++) {
      float v = tanhf(acc[ta][j] + bias);
      float vup = __shfl(v, src_up);
      float vdn = __shfl(v, src_dn);
      if (l15 < 7) {
        float o = v;
        if (l15 == 1) o += vup;
        if (l15 == 5) o += vdn;
        if (l15 == 3) o = 0.f;
        cum[cb + (size_t)l15*HWq + pxb + j] = o;
      }
    }
  }
}

// ---------------------------------------------------------------------------
// MERGED deformable sample + einsum via MFMA v3 (R25-validated):
// unified morph addressing, RUNTIME 7-tap loop, software pipeline
// ISSUE(k+1) || MFMA(k) || WRITE(k+1) with 2 LDS slots, depth 1.
// 32 px/wave, ch-split staging; BARRIER-FREE (intra-wave LDS, in-order DS).
// ---------------------------------------------------------------------------
__global__ __launch_bounds__(64, 3) void einsum_mfma_kernel(
    const unsigned short* __restrict__ fpH, const unsigned short* __restrict__ fpV,
    const float* __restrict__ cumH, const float* __restrict__ cumV,
    const unsigned short* __restrict__ wtpHp, const unsigned short* __restrict__ wtpVp,
    const float* __restrict__ dscbH, const float* __restrict__ dscbV,
    float* __restrict__ outH, float* __restrict__ outV,
    float* __restrict__ pstat)
{
  __shared__ __align__(16) unsigned short sA[2*32*64];  // 8 KB, 2 tap slots
  const size_t HW8 = (size_t)HWq*8;
  int morph = blockIdx.y;
  const unsigned short* fp  = morph ? fpV   : fpH;
  const float* cum          = morph ? cumV  : cumH;
  const unsigned short* wtp = morph ? wtpVp : wtpHp;
  const float* dsc_b        = morph ? dscbV : dscbH;
  float* out                = morph ? outV  : outH;
  int bid = blockIdx.x;                    // 0..2303
  int swz = (bid & 7)*288 + (bid >> 3);    // XCD-banded
  int b   = swz / 1152;
  int blk = swz % 1152;
  int l = threadIdx.x;                     // 0..63
  int l15 = l & 15, lg = l >> 4;
  int l7 = l & 7;
  int px5 = l & 31;                        // px within wave
  int chh = l >> 5;                        // channel half
  int p = blk*32 + px5;
  int r = p / Wq, c = p % Wq;

  int fixc   = morph ? r : c;              // coordinate that gets +k-3
  int vbase  = morph ? c : r;              // coordinate that gets cum offset
  int stride = morph ? 1 : Wq;

  f32x4 acc[2][4];
#pragma unroll
  for (int i = 0; i < 2; i++)
#pragma unroll
    for (int j = 0; j < 4; j++) acc[i][j] = (f32x4){0.f,0.f,0.f,0.f};

  const unsigned short* fb = fp + (size_t)b*HWq*128;

  f16x8 a0r[4], a1r[4];
  float w0, w1;
  bool oob;

#define ISSUE(KK)                                                           \
  {                                                                         \
    int fx = fixc + (KK) - 3;                                               \
    oob = (fx < 0 || fx >= 192);                                            \
    float vf = (float)vbase + cum[((size_t)(b*7 + (KK)))*HWq + p];          \
    float v0 = floorf(vf);                                                  \
    int v0q = (int)v0;                                                      \
    int v0i = min(max(v0q, 0), 191);                                        \
    int v1i = min(max(v0q + 1, 0), 191);                                    \
    float v0f = fminf(fmaxf(v0, 0.f), 192.f);                               \
    float v1f = fminf(fmaxf(v0 + 1.f, 0.f), 192.f);                         \
    w0 = v1f - vf; w1 = vf - v0f;                                           \
    int fixoff = morph ? fx*Wq : fx;                                        \
    const unsigned short* p0 = fb + (size_t)(fixoff + v0i*stride)*8;        \
    const unsigned short* p1 = fb + (size_t)(fixoff + v1i*stride)*8;        \
    if (!oob) {                                                             \
      _Pragma("unroll")                                                     \
      for (int gi = 0; gi < 4; gi++) {                                      \
        int g = chh*4 + gi;                                                 \
        a0r[gi] = *(const f16x8*)(p0 + (size_t)g*HW8);                      \
        a1r[gi] = *(const f16x8*)(p1 + (size_t)g*HW8);                      \
      }                                                                     \
    }                                                                       \
  }

#define WRITE(SLOT)                                                         \
  {                                                                         \
    unsigned short* myrow = sA + (size_t)((SLOT)*32 + px5)*64;              \
    if (oob) {                                                              \
      uint4 z = {0u,0u,0u,0u};                                              \
      _Pragma("unroll")                                                     \
      for (int gi = 0; gi < 4; gi++)                                        \
        *(uint4*)(myrow + (size_t)(((chh*4 + gi) ^ l7))*8) = z;             \
    } else {                                                                \
      _Pragma("unroll")                                                     \
      for (int gi = 0; gi < 4; gi++) {                                      \
        f16x8 sh;                                                           \
        _Pragma("unroll")                                                   \
        for (int e = 0; e < 8; e++) {                                       \
          float v = w0*(float)a0r[gi][e] + w1*(float)a1r[gi][e];            \
          sh[e] = (_Float16)v;                                              \
        }                                                                   \
        *(f16x8*)(myrow + (size_t)(((chh*4 + gi) ^ l7))*8) = sh;            \
      }                                                                     \
    }                                                                       \
  }

#define MFMA_TAP(KK, SLOT)                                                  \
  {                                                                         \
    _Pragma("unroll")                                                       \
    for (int kc = 0; kc < 2; kc++) {                                        \
      const unsigned short* wbase = wtp + (size_t)(((KK)*2 + kc)*2)*2048;   \
      f16x8 bh[4], bl[4];                                                   \
      _Pragma("unroll")                                                     \
      for (int tb = 0; tb < 4; tb++) {                                      \
        bh[tb] = *(const f16x8*)(wbase + (tb*16 + l15)*32 + lg*8);          \
        bl[tb] = *(const f16x8*)(wbase + 2048 + (tb*16 + l15)*32 + lg*8);   \
      }                                                                     \
      f16x8 ah[2];                                                          \
      _Pragma("unroll")                                                     \
      for (int ta = 0; ta < 2; ta++) {                                      \
        const unsigned short* rbase = sA + (size_t)((SLOT)*32 + ta*16 + l15)*64; \
        ah[ta] = *(const f16x8*)(rbase + (size_t)((kc*4 + lg) ^ l7)*8);     \
      }                                                                     \
      _Pragma("unroll")                                                     \
      for (int ta = 0; ta < 2; ta++)                                        \
        _Pragma("unroll")                                                   \
        for (int tb = 0; tb < 4; tb++) {                                    \
          acc[ta][tb] = __builtin_amdgcn_mfma_f32_16x16x32_f16(ah[ta], bh[tb], acc[ta][tb], 0, 0, 0); \
          acc[ta][tb] = __builtin_amdgcn_mfma_f32_16x16x32_f16(ah[ta], bl[tb], acc[ta][tb], 0, 0, 0); \
        }                                                                   \
    }                                                                       \
  }

  ISSUE(0);
  WRITE(0);
#pragma unroll 1
  for (int k = 0; k < 7; k++) {
    int slot = k & 1;
    if (k < 6) ISSUE(k+1);          // next-tap loads in flight across MFMA
    MFMA_TAP(k, slot);              // lgkm waits on WRITE(k)
    if (k < 6) WRITE((k+1) & 1);    // vmcnt wait + lerp + ds_write
  }
#undef ISSUE
#undef WRITE
#undef MFMA_TAP

  int pbase = blk*32;
#pragma unroll
  for (int tb = 0; tb < 4; tb++) {
    int oc = tb*16 + l15;
    float bias = dsc_b[oc];
    float* dst = out + (size_t)(b*64 + oc)*HWq + pbase;
    float s = 0.f, ss = 0.f;
#pragma unroll
    for (int ta = 0; ta < 2; ta++) {
      f32x4 v = acc[ta][tb];
      float v0 = v[0]+bias, v1 = v[1]+bias, v2 = v[2]+bias, v3 = v[3]+bias;
      *(float4*)(dst + ta*16 + lg*4) = make_float4(v0, v1, v2, v3);
      s  += v0 + v1 + v2 + v3;
      ss += v0*v0 + v1*v1 + v2*v2 + v3*v3;
    }
    s  += __shfl_xor(s, 16);
    s  += __shfl_xor(s, 32);
    ss += __shfl_xor(ss, 16);
    ss += __shfl_xor(ss, 32);
    if (lg == 0) {
      float* pp = pstat + ((size_t)(morph*2304 + swz))*128 + oc*2;
      pp[0] = s; pp[1] = ss;
    }
  }
}

// ---------------------------------------------------------------------------
// GN partial reduce: grid 256 (one block per (buf,b,ch)), reads pstat.
// ---------------------------------------------------------------------------
__global__ __launch_bounds__(256) void gnred_kernel(const float* __restrict__ pstat,
                                                    float* __restrict__ stats)
{
  int combo = blockIdx.x;           // buf*128 + b*64 + ch
  int buf = combo >> 7;
  int rem = combo & 127;
  int b = rem >> 6, ch = rem & 63;
  int t = threadIdx.x;
  float s = 0.f, ss = 0.f;
  for (int q = t; q < 1152; q += 256) {
    const float* pp = pstat + ((size_t)(buf*2304 + b*1152 + q))*128 + ch*2;
    s += pp[0]; ss += pp[1];
  }
  __shared__ float red[2][4];
  for (int off = 32; off; off >>= 1) {
    s  += __shfl_down(s, off);
    ss += __shfl_down(ss, off);
  }
  if ((t & 63) == 0) { red[0][t >> 6] = s; red[1][t >> 6] = ss; }
  __syncthreads();
  if (t == 0) {
    s  = red[0][0] + red[0][1] + red[0][2] + red[0][3];
    ss = red[1][0] + red[1][1] + red[1][2] + red[1][3];
    stats[combo*2 + 0] = s;
    stats[combo*2 + 1] = ss;
  }
}

__global__ __launch_bounds__(256) void gnfinal_kernel(const float* __restrict__ stats,
                                                      const float* __restrict__ h_gn_g, const float* __restrict__ h_gn_b,
                                                      const float* __restrict__ v_gn_g, const float* __restrict__ v_gn_b,
                                                      float* __restrict__ gnAB)
{
  int t = threadIdx.x;
  int buf = t >> 7, ch = t & 63;
  int base = t & ~3;
  float sum = 0.f, ss = 0.f;
#pragma unroll
  for (int q = 0; q < 4; q++) { sum += stats[(base+q)*2]; ss += stats[(base+q)*2 + 1]; }
  const float n = 4.f * HWq;
  float mean = sum / n;
  float var = ss / n - mean*mean;
  float gg = (buf ? v_gn_g : h_gn_g)[ch];
  float bb = (buf ? v_gn_b : h_gn_b)[ch];
  float A = gg / sqrtf(var + 1e-5f);
  gnAB[t*2 + 0] = A;
  gnAB[t*2 + 1] = bb - mean*A;
}

// ---------------------------------------------------------------------------
// FUSED: comb = relu(GN(h)) + relu(GN(v)) + x1 inline, then 1x1 conv + SiLU
// ---------------------------------------------------------------------------
__global__ __launch_bounds__(256) void final2_kernel(const float* __restrict__ hbuf,
                                                     const float* __restrict__ vbuf,
                                                     const float* __restrict__ x1,
                                                     const float* __restrict__ gnAB,
                                                     const float* __restrict__ lwT,
                                                     const float* __restrict__ lbO,
                                                     float* __restrict__ out)
{
  int b = blockIdx.y;
  int p = blockIdx.x*256 + threadIdx.x;
  float acc[64];
#pragma unroll
  for (int o = 0; o < 64; o++) acc[o] = 0.f;
  for (int i = 0; i < 64; i++) {
    size_t off = (size_t)(b*64 + i)*HWq + p;
    int plane = b*64 + i;
    int ih = plane*2;
    int iv = (128 + plane)*2;
    float hv = fmaxf(hbuf[off]*gnAB[ih] + gnAB[ih+1], 0.f);
    float vv = fmaxf(vbuf[off]*gnAB[iv] + gnAB[iv+1], 0.f);
    float cv = hv + vv + x1[off];
    const float* wr = lwT + i*64;
#pragma unroll
    for (int o = 0; o < 64; o++) acc[o] += cv * wr[o];
  }
  float* dst = out + (size_t)b*Cq*HWq + p;
#pragma unroll
  for (int o = 0; o < 64; o++) {
    float yv = acc[o] + lbO[o];
    dst[(size_t)o*HWq] = yv / (1.f + expf(-yv));
  }
}

// ---------------------------------------------------------------------------
extern "C" void kernel_launch(void* const* d_in, const int* in_sizes, int n_in,
                              void* d_out, int out_size, void* d_ws, size_t ws_size,
                              hipStream_t stream)
{
  const float* x       = (const float*)d_in[0];
  const float* w_first = (const float*)d_in[1];
  float* ws = (float*)d_ws;

  float* bufA = ws;            // conv7 out -> h-einsum-out
  float* bufB = ws + Nq;       // v-einsum-out
  float* x1   = ws + 2*Nq;
  float* h_ds = ws + 3*Nq;     // xpack -> fpackH
  float* v_ds = ws + 4*Nq;     // fpackV
  size_t off = 5*Nq;
  float* hcum  = ws + off; off += (size_t)Bq*7*HWq;
  float* vcum  = ws + off; off += (size_t)Bq*7*HWq;
  float* wEffH = ws + off; off += 64*19;
  float* bEffH = ws + off; off += 64;
  float* wEffV = ws + off; off += 64*19;
  float* bEffV = ws + off; off += 64;
  float* wtH   = ws + off; off += 64*64*7;   // holds wtpH f16 pack
  float* wtV   = ws + off; off += 64*64*7;   // holds wtpV f16 pack
  float* wOpHf = ws + off; off += 9216;      // offset B-pack H (18432 f16)
  float* wOpVf = ws + off; off += 9216;      // offset B-pack V
  float* bOffH = ws + off; off += 8;
  float* bOffV = ws + off; off += 8;
  float* lwT   = ws + off; off += 64*64;
  float* lbO   = ws + off; off += 64;
  float* stats = ws + off; off += 512;
  float* gnAB  = ws + off; off += 512;
  float* wB    = ws + off; off += 2*64*18*20;
  float* pstat = ws + off; off += (size_t)2*2304*128;
  unsigned short* wpack = (unsigned short*)(ws + off); off += 2*49*2*64*32/2 + 16;
  unsigned short* xpack  = (unsigned short*)h_ds;
  unsigned short* fpackH = (unsigned short*)h_ds;
  unsigned short* fpackV = (unsigned short*)v_ds;
  unsigned short* wtpH = (unsigned short*)wtH;
  unsigned short* wtpV = (unsigned short*)wtV;
  unsigned short* wOpH = (unsigned short*)wOpHf;
  unsigned short* wOpV = (unsigned short*)wOpVf;

  prep_all_kernel<<<dim3(74), dim3(256), 0, stream>>>(
      (const float*)d_in[2],  (const float*)d_in[3],  (const float*)d_in[4],  (const float*)d_in[5],
      (const float*)d_in[6],  (const float*)d_in[7],
      (const float*)d_in[8],  (const float*)d_in[9],  (const float*)d_in[10], (const float*)d_in[11],
      (const float*)d_in[12], (const float*)d_in[13],
      (const float*)d_in[14], (const float*)d_in[15], (const float*)d_in[16], (const float*)d_in[17],
      (const float*)d_in[18], (const float*)d_in[19],
      (const float*)d_in[24], (const float*)d_in[25], (const float*)d_in[26], (const float*)d_in[27],
      (const float*)d_in[28], (const float*)d_in[29],
      (const float*)d_in[34], (const float*)d_in[35], (const float*)d_in[36], (const float*)d_in[37],
      (const float*)d_in[38],
      w_first, (const float*)d_in[20], (const float*)d_in[30],
      wEffH, bEffH, wEffV, bEffV, wOpH, wOpV, bOffH, bOffV, lwT, lbO, wB,
      wtpH, wtpV, wpack);

  tof16_pack_kernel<<<dim3(Hq, Bq), dim3(192), 0, stream>>>(x, xpack);
  conv7_mfma_kernel<<<dim3(4, 96, 2), dim3(256), 0, stream>>>(xpack, wpack, bufA);

  pool_fused_kernel<<<dim3(6, 128), dim3(256), 0, stream>>>(bufA, x1);

  dwf_kernel<<<dim3(144, 8, 4), dim3(256), 0, stream>>>(x1, wEffH, bEffH, wB,
      wEffV, bEffV, wB + 64*18*20, fpackH, fpackV);

  off_cum_kernel<<<dim3(4608), dim3(64), 0, stream>>>(fpackH, fpackV,
      wOpH, wOpV, bOffH, bOffV, hcum, vcum);

  einsum_mfma_kernel<<<dim3(2304, 2), dim3(64), 0, stream>>>(fpackH, fpackV,
      hcum, vcum, wtpH, wtpV, (const float*)d_in[21], (const float*)d_in[31], bufA, bufB, pstat);

  gnred_kernel<<<dim3(256), dim3(256), 0, stream>>>(pstat, stats);
  gnfinal_kernel<<<dim3(1), dim3(256), 0, stream>>>(stats,
      (const float*)d_in[22], (const float*)d_in[23],
      (const float*)d_in[32], (const float*)d_in[33], gnAB);

  final2_kernel<<<dim3(144, 2), dim3(256), 0, stream>>>(bufA, bufB, x1, gnAB, lwT, lbO, (float*)d_out);
}